// Round 2
// baseline (2134.497 us; speedup 1.0000x reference)
//
#include <hip/hip_runtime.h>
#include <math.h>

constexpr int BS = 2, C_IN = 8, CTX = 1024, TGT = 96;
constexpr int DM = 256, NH = 16, DFF = 1024, NL = 4;
constexpr int NF = 256, TOTAL = 320;
constexpr int NB = 16;   // BS * C_IN sequences
constexpr int DK = 16;
constexpr float EPS = 1e-5f;
constexpr float SCALE = 0.25f;  // DK^-0.5

// ---------------- RevIN: per-(b,c) mean/std over CTX, normalize ----------------
__global__ void k_revin(const float* __restrict__ z, const float* __restrict__ rw,
                        const float* __restrict__ rb, float* __restrict__ zn,
                        float* __restrict__ meanv, float* __restrict__ stdv) {
    int bc = blockIdx.x, t = threadIdx.x;
    __shared__ float r1[256], r2[256];
    float s1 = 0.f, s2 = 0.f;
    for (int i = t; i < CTX; i += 256) {
        float x = z[bc * CTX + i];
        s1 += x; s2 += x * x;
    }
    r1[t] = s1; r2[t] = s2; __syncthreads();
    for (int off = 128; off > 0; off >>= 1) {
        if (t < off) { r1[t] += r1[t + off]; r2[t] += r2[t + off]; }
        __syncthreads();
    }
    float m = r1[0] * (1.0f / CTX);
    float var = r2[0] * (1.0f / CTX) - m * m;
    float sd = sqrtf(var + EPS);
    float w = rw[bc % C_IN], b = rb[bc % C_IN];
    float inv = 1.0f / sd;
    for (int i = t; i < CTX; i += 256) {
        float x = z[bc * CTX + i];
        zn[bc * CTX + i] = (x - m) * inv * w + b;
    }
    if (t == 0) { meanv[bc] = m; stdv[bc] = sd; }
}

// ---------------- dual-scale patch embed + positional ----------------
__global__ void k_embed(const float* __restrict__ zn, const float* __restrict__ Wf,
                        const float* __restrict__ bfv, const float* __restrict__ Wc,
                        const float* __restrict__ bcv, const float* __restrict__ Wpos,
                        float* __restrict__ u) {
    int bc = blockIdx.x / TOTAL, p = blockIdx.x % TOTAL, d = threadIdx.x;
    float acc;
    if (p < NF) {
        acc = bfv[d];
        int base = p * 4;
        for (int i = 0; i < 8; i++) {
            int idx = min(base + i, CTX - 1);  // replication pad
            acc += zn[bc * CTX + idx] * Wf[i * DM + d];
        }
    } else {
        int pc = p - NF;
        acc = bcv[d];
        int base = pc * 16;
        for (int i = 0; i < 32; i++) {
            int idx = min(base + i, CTX - 1);
            acc += zn[bc * CTX + idx] * Wc[i * DM + d];
        }
    }
    acc += Wpos[p * DM + d];
    u[(bc * TOTAL + p) * DM + d] = acc;
}

// ---------------- fp32 tiled GEMM: C = A(MxK) @ W(KxN) + bias, opt GELU ----------------
template <int GELU>
__global__ void k_gemm(const float* __restrict__ A, const float* __restrict__ W,
                       const float* __restrict__ bias, float* __restrict__ C,
                       int M, int N, int K) {
    __shared__ float As[16][64];
    __shared__ float Bs[16][64];
    int tid = threadIdx.x;
    int tx = tid & 15, ty = tid >> 4;
    int m0 = blockIdx.y * 64, n0 = blockIdx.x * 64;
    float acc[4][4] = {};
    for (int k0 = 0; k0 < K; k0 += 16) {
        for (int r = 0; r < 4; r++) {
            int idx = tid + r * 256;
            int kka = idx & 15, mm = idx >> 4;
            As[kka][mm] = A[(m0 + mm) * K + k0 + kka];
            int nn = idx & 63, kkb = idx >> 6;
            Bs[kkb][nn] = W[(k0 + kkb) * N + n0 + nn];
        }
        __syncthreads();
        for (int kk = 0; kk < 16; kk++) {
            float a[4], b[4];
            for (int i = 0; i < 4; i++) a[i] = As[kk][ty * 4 + i];
            for (int j = 0; j < 4; j++) b[j] = Bs[kk][tx * 4 + j];
            for (int i = 0; i < 4; i++)
                for (int j = 0; j < 4; j++) acc[i][j] += a[i] * b[j];
        }
        __syncthreads();
    }
    for (int i = 0; i < 4; i++)
        for (int j = 0; j < 4; j++) {
            int n = n0 + tx * 4 + j;
            float vv = acc[i][j] + bias[n];
            if (GELU) vv = vv * 0.5f * (1.0f + erff(vv * 0.70710678118f));
            C[(m0 + ty * 4 + i) * N + n] = vv;
        }
}

// ---------------- attention scores: s (+)= scale * Q K^T, per (b,h) ----------------
__global__ void k_scores(const float* __restrict__ q, const float* __restrict__ k,
                         float* __restrict__ s, int accum) {
    // grid (NB*NH, TOTAL/16, TOTAL/16), block 256
    int bh = blockIdx.x, b = bh >> 4, h = bh & 15;
    int i0 = blockIdx.y * 16, j0 = blockIdx.z * 16;
    int tx = threadIdx.x & 15, ty = threadIdx.x >> 4;
    __shared__ float Qs[16][17], Ks[16][17];
    Qs[ty][tx] = q[(b * TOTAL + i0 + ty) * DM + h * DK + tx];
    Ks[ty][tx] = k[(b * TOTAL + j0 + ty) * DM + h * DK + tx];
    __syncthreads();
    float acc = 0.f;
    for (int d = 0; d < 16; d++) acc += Qs[ty][d] * Ks[tx][d];
    acc *= SCALE;
    int idx = (bh * TOTAL + i0 + ty) * TOTAL + j0 + tx;
    if (accum) s[idx] += acc; else s[idx] = acc;
}

// ---------------- fused softmax(row of s) @ V -> attn out ----------------
__global__ void k_softmax_pv(const float* __restrict__ s, const float* __restrict__ v,
                             float* __restrict__ ao) {
    // grid (NB*NH, TOTAL), block 320
    int bh = blockIdx.x, b = bh >> 4, h = bh & 15, i = blockIdx.y;
    int t = threadIdx.x;
    __shared__ float red[320];
    __shared__ float w[320];
    __shared__ float pr[20][16];
    float sv = s[(bh * TOTAL + i) * TOTAL + t];
    red[t] = sv; __syncthreads();
    for (int off = 256; off > 0; off >>= 1) {
        if (t < off && t + off < TOTAL) red[t] = fmaxf(red[t], red[t + off]);
        __syncthreads();
    }
    float mx = red[0]; __syncthreads();
    float ev = expf(sv - mx);
    red[t] = ev; __syncthreads();
    for (int off = 256; off > 0; off >>= 1) {
        if (t < off && t + off < TOTAL) red[t] += red[t + off];
        __syncthreads();
    }
    float denom = red[0];
    w[t] = ev / denom;
    __syncthreads();
    int g = t >> 4, d = t & 15;
    float p = 0.f;
    for (int m = 0; m < 16; m++) {
        int j = g + 20 * m;
        p += w[j] * v[(b * TOTAL + j) * DM + h * DK + d];
    }
    pr[g][d] = p; __syncthreads();
    if (t < 16) {
        float acc = 0.f;
        for (int gg = 0; gg < 20; gg++) acc += pr[gg][t];
        ao[(b * TOTAL + i) * DM + h * DK + t] = acc;
    }
}

// ---------------- residual add + LayerNorm (in place on u) ----------------
__global__ void k_add_ln(float* __restrict__ u, const float* __restrict__ o,
                         const float* __restrict__ ls, const float* __restrict__ lb) {
    int row = blockIdx.x, d = threadIdx.x;
    __shared__ float r1[256], r2[256];
    float x = u[row * DM + d] + o[row * DM + d];
    r1[d] = x; r2[d] = x * x; __syncthreads();
    for (int off = 128; off > 0; off >>= 1) {
        if (d < off) { r1[d] += r1[d + off]; r2[d] += r2[d + off]; }
        __syncthreads();
    }
    float m = r1[0] * (1.0f / DM);
    float var = r2[0] * (1.0f / DM) - m * m;
    float rs = rsqrtf(var + EPS);
    u[row * DM + d] = (x - m) * rs * ls[d] + lb[d];
}

// ---------------- transpose u (bc,p,d) -> zzT (bc, d*TOTAL+p) ----------------
__global__ void k_transpose(const float* __restrict__ u, float* __restrict__ zzT) {
    __shared__ float tile[32][33];
    int bc = blockIdx.x, p0 = blockIdx.y * 32, d0 = blockIdx.z * 32;
    int tx = threadIdx.x, ty = threadIdx.y;
    tile[ty][tx] = u[(bc * TOTAL + p0 + ty) * DM + d0 + tx];
    __syncthreads();
    zzT[bc * (DM * TOTAL) + (d0 + ty) * TOTAL + p0 + tx] = tile[tx][ty];
}

// ---------------- head GEMM: acc += zzT(16x81920) @ Wh(81920x96) ----------------
__global__ void k_head(const float* __restrict__ zzT, const float* __restrict__ Wh,
                       float* __restrict__ acc_head) {
    // grid (TGT/16, 80), block 256: tx = col-in-tile, ty = bc
    int t0 = blockIdx.x * 16;
    int k0 = blockIdx.y * 1024;
    int tx = threadIdx.x & 15, ty = threadIdx.x >> 4;
    __shared__ float whs[16][17];
    __shared__ float zs[16][17];
    float acc = 0.f;
    for (int kb = 0; kb < 1024; kb += 16) {
        whs[ty][tx] = Wh[(k0 + kb + ty) * TGT + t0 + tx];
        zs[ty][tx] = zzT[ty * (DM * TOTAL) + k0 + kb + tx];
        __syncthreads();
        for (int kk = 0; kk < 16; kk++) acc += zs[ty][kk] * whs[kk][tx];
        __syncthreads();
    }
    atomicAdd(&acc_head[ty * TGT + t0 + tx], acc);
}

// ---------------- final: bias + RevIN denorm -> out ----------------
__global__ void k_final(const float* __restrict__ acc_head, const float* __restrict__ bh,
                        const float* __restrict__ rw, const float* __restrict__ rb,
                        const float* __restrict__ meanv, const float* __restrict__ stdv,
                        float* __restrict__ out) {
    int idx = blockIdx.x * 256 + threadIdx.x;
    if (idx >= NB * TGT) return;
    int bc = idx / TGT, t = idx % TGT, c = bc % C_IN;
    float vv = acc_head[idx] + bh[t];
    vv = (vv - rb[c]) / (rw[c] + EPS * EPS) * stdv[bc] + meanv[bc];
    out[idx] = vv;
}

extern "C" void kernel_launch(void* const* d_in, const int* in_sizes, int n_in,
                              void* d_out, int out_size, void* d_ws, size_t ws_size,
                              hipStream_t stream) {
    const float* z       = (const float*)d_in[0];
    const float* revin_w = (const float*)d_in[1];
    const float* revin_b = (const float*)d_in[2];
    const float* Wf      = (const float*)d_in[3];
    const float* bfv     = (const float*)d_in[4];
    const float* Wc      = (const float*)d_in[5];
    const float* bcv     = (const float*)d_in[6];
    const float* Wpos    = (const float*)d_in[7];
    const float* WQ      = (const float*)d_in[8];
    const float* bQ      = (const float*)d_in[9];
    const float* WK      = (const float*)d_in[10];
    const float* bK      = (const float*)d_in[11];
    const float* WV      = (const float*)d_in[12];
    const float* bV      = (const float*)d_in[13];
    const float* WO      = (const float*)d_in[14];
    const float* bO      = (const float*)d_in[15];
    const float* ln1s    = (const float*)d_in[16];
    const float* ln1b    = (const float*)d_in[17];
    const float* ln2s    = (const float*)d_in[18];
    const float* ln2b    = (const float*)d_in[19];
    const float* F1      = (const float*)d_in[20];
    const float* c1      = (const float*)d_in[21];
    const float* F2      = (const float*)d_in[22];
    const float* c2      = (const float*)d_in[23];
    const float* Wh      = (const float*)d_in[24];
    const float* bh      = (const float*)d_in[25];
    float* out = (float*)d_out;

    float* wsf = (float*)d_ws;
    float* meanv = wsf;  wsf += 16;
    float* stdv  = wsf;  wsf += 16;
    float* zn    = wsf;  wsf += NB * CTX;
    float* u     = wsf;  wsf += NB * TOTAL * DM;
    float* q     = wsf;  wsf += NB * TOTAL * DM;   // also reused for attn-out and zzT
    float* k     = wsf;  wsf += NB * TOTAL * DM;
    float* v     = wsf;  wsf += NB * TOTAL * DM;
    float* o     = wsf;  wsf += NB * TOTAL * DM;
    float* h     = wsf;  wsf += NB * TOTAL * DFF;
    float* s     = wsf;  wsf += NB * NH * TOTAL * TOTAL;   // 104.9 MB residual scores
    float* acc_head = wsf; wsf += NB * TGT;

    const int M = NB * TOTAL;  // 5120

    k_revin<<<NB, 256, 0, stream>>>(z, revin_w, revin_b, zn, meanv, stdv);
    k_embed<<<NB * TOTAL, 256, 0, stream>>>(zn, Wf, bfv, Wc, bcv, Wpos, u);

    for (int l = 0; l < NL; l++) {
        k_gemm<0><<<dim3(DM / 64, M / 64), 256, 0, stream>>>(u, WQ + l * DM * DM, bQ + l * DM, q, M, DM, DM);
        k_gemm<0><<<dim3(DM / 64, M / 64), 256, 0, stream>>>(u, WK + l * DM * DM, bK + l * DM, k, M, DM, DM);
        k_gemm<0><<<dim3(DM / 64, M / 64), 256, 0, stream>>>(u, WV + l * DM * DM, bV + l * DM, v, M, DM, DM);
        k_scores<<<dim3(NB * NH, TOTAL / 16, TOTAL / 16), 256, 0, stream>>>(q, k, s, l > 0 ? 1 : 0);
        k_softmax_pv<<<dim3(NB * NH, TOTAL), 320, 0, stream>>>(s, v, q);  // q := attn concat out
        k_gemm<0><<<dim3(DM / 64, M / 64), 256, 0, stream>>>(q, WO + l * DM * DM, bO + l * DM, o, M, DM, DM);
        k_add_ln<<<M, 256, 0, stream>>>(u, o, ln1s + l * DM, ln1b + l * DM);
        k_gemm<1><<<dim3(DFF / 64, M / 64), 256, 0, stream>>>(u, F1 + l * DM * DFF, c1 + l * DFF, h, M, DFF, DM);
        k_gemm<0><<<dim3(DM / 64, M / 64), 256, 0, stream>>>(h, F2 + l * DFF * DM, c2 + l * DM, o, M, DM, DFF);
        k_add_ln<<<M, 256, 0, stream>>>(u, o, ln2s + l * DM, ln2b + l * DM);
    }

    // head: transpose u into zzT (reuse q), accumulate, finalize
    k_transpose<<<dim3(NB, TOTAL / 32, DM / 32), dim3(32, 32), 0, stream>>>(u, q);
    hipMemsetAsync(acc_head, 0, NB * TGT * sizeof(float), stream);
    k_head<<<dim3(TGT / 16, 80), 256, 0, stream>>>(q, Wh, acc_head);
    k_final<<<(NB * TGT + 255) / 256, 256, 0, stream>>>(acc_head, bh, revin_w, revin_b, meanv, stdv, out);
}

// Round 3
// 1152.278 us; speedup vs baseline: 1.8524x; 1.8524x over previous
//
#include <hip/hip_runtime.h>
#include <math.h>

typedef unsigned short ushort;
typedef unsigned int uint;
typedef __attribute__((ext_vector_type(8))) short short8;
typedef __attribute__((ext_vector_type(4))) float f32x4;

constexpr int BS = 2, C_IN = 8, CTX = 1024, TGT = 96;
constexpr int DM = 256, NH = 16, DFF = 1024, NL = 4;
constexpr int NF = 256, TOTAL = 320;
constexpr int NB = 16;   // BS * C_IN sequences
constexpr int DK = 16;
constexpr float EPS = 1e-5f;
constexpr float SCALE = 0.25f;  // DK^-0.5

__device__ __forceinline__ ushort f2b(float x) {
    uint u = __float_as_uint(x);
    u += 0x7fff + ((u >> 16) & 1);   // round-to-nearest-even
    return (ushort)(u >> 16);
}

// ---------------- RevIN ----------------
__global__ void k_revin(const float* __restrict__ z, const float* __restrict__ rw,
                        const float* __restrict__ rb, float* __restrict__ zn,
                        float* __restrict__ meanv, float* __restrict__ stdv) {
    int bc = blockIdx.x, t = threadIdx.x;
    __shared__ float r1[256], r2[256];
    float s1 = 0.f, s2 = 0.f;
    for (int i = t; i < CTX; i += 256) {
        float x = z[bc * CTX + i];
        s1 += x; s2 += x * x;
    }
    r1[t] = s1; r2[t] = s2; __syncthreads();
    for (int off = 128; off > 0; off >>= 1) {
        if (t < off) { r1[t] += r1[t + off]; r2[t] += r2[t + off]; }
        __syncthreads();
    }
    float m = r1[0] * (1.0f / CTX);
    float var = r2[0] * (1.0f / CTX) - m * m;
    float sd = sqrtf(var + EPS);
    float w = rw[bc % C_IN], b = rb[bc % C_IN];
    float inv = 1.0f / sd;
    for (int i = t; i < CTX; i += 256) {
        float x = z[bc * CTX + i];
        zn[bc * CTX + i] = (x - m) * inv * w + b;
    }
    if (t == 0) { meanv[bc] = m; stdv[bc] = sd; }
}

// ---------------- dual-scale patch embed + positional ----------------
__global__ void k_embed(const float* __restrict__ zn, const float* __restrict__ Wf,
                        const float* __restrict__ bfv, const float* __restrict__ Wc,
                        const float* __restrict__ bcv, const float* __restrict__ Wpos,
                        float* __restrict__ u) {
    int bc = blockIdx.x / TOTAL, p = blockIdx.x % TOTAL, d = threadIdx.x;
    float acc;
    if (p < NF) {
        acc = bfv[d];
        int base = p * 4;
        for (int i = 0; i < 8; i++) {
            int idx = min(base + i, CTX - 1);
            acc += zn[bc * CTX + idx] * Wf[i * DM + d];
        }
    } else {
        int pc = p - NF;
        acc = bcv[d];
        int base = pc * 16;
        for (int i = 0; i < 32; i++) {
            int idx = min(base + i, CTX - 1);
            acc += zn[bc * CTX + idx] * Wc[i * DM + d];
        }
    }
    acc += Wpos[p * DM + d];
    u[(bc * TOTAL + p) * DM + d] = acc;
}

// ---------------- bf16 MFMA GEMM body: C = A(MxK) @ W(KxN) + bias [+GELU] ----------------
// 64x64 block tile, 4 waves, each wave: 16 rows x 64 cols (4 MFMA 16x16x32 tiles), BK=32.
template <int GELU>
__device__ __forceinline__ void gemm_body(const float* __restrict__ A,
                                          const float* __restrict__ W,
                                          const float* __restrict__ bias,
                                          float* __restrict__ C,
                                          int M, int N, int K,
                                          int m0, int n0) {
    __shared__ ushort Asb[64][40];   // [m][k], pad 8 -> 80B row stride (16B aligned)
    __shared__ ushort Bsb[64][40];   // [n][k] (transposed), same pad
    int tid = threadIdx.x;
    int wave = tid >> 6, lane = tid & 63;
    int quad = lane >> 4, l16 = lane & 15;

    f32x4 acc[4];
    for (int nt = 0; nt < 4; nt++) acc[nt] = (f32x4){0.f, 0.f, 0.f, 0.f};

    for (int k0 = 0; k0 < K; k0 += 32) {
        // stage A: thread t -> row=t>>2, kc=(t&3)*8 : 8 consecutive k
        {
            int row = tid >> 2, kc = (tid & 3) * 8;
            const float* ga = &A[(m0 + row) * K + k0 + kc];
            union { short8 v; ushort s[8]; } tmp;
#pragma unroll
            for (int j = 0; j < 8; j++) tmp.s[j] = f2b(ga[j]);
            *(short8*)&Asb[row][kc] = tmp.v;
        }
        // stage B (transpose to [n][k]): thread t -> n=t&63, kg=(t>>6)*8
        {
            int n = tid & 63, kg = (tid >> 6) * 8;
            union { short8 v; ushort s[8]; } tmp;
#pragma unroll
            for (int j = 0; j < 8; j++) tmp.s[j] = f2b(W[(k0 + kg + j) * N + n0 + n]);
            *(short8*)&Bsb[n][kg] = tmp.v;
        }
        __syncthreads();
        short8 af = *(const short8*)&Asb[wave * 16 + l16][quad * 8];
#pragma unroll
        for (int nt = 0; nt < 4; nt++) {
            short8 bf = *(const short8*)&Bsb[nt * 16 + l16][quad * 8];
            acc[nt] = __builtin_amdgcn_mfma_f32_16x16x32_bf16(af, bf, acc[nt], 0, 0, 0);
        }
        __syncthreads();
    }
#pragma unroll
    for (int nt = 0; nt < 4; nt++) {
        int col = n0 + nt * 16 + l16;
        float bi = bias[col];
#pragma unroll
        for (int r = 0; r < 4; r++) {
            int row = m0 + wave * 16 + quad * 4 + r;
            float vv = acc[nt][r] + bi;
            if (GELU) vv = vv * 0.5f * (1.0f + erff(vv * 0.70710678118f));
            C[row * N + col] = vv;
        }
    }
}

template <int GELU>
__global__ __launch_bounds__(256) void k_gemm_mfma(const float* __restrict__ A,
                                                   const float* __restrict__ W,
                                                   const float* __restrict__ bias,
                                                   float* __restrict__ C,
                                                   int M, int N, int K) {
    gemm_body<GELU>(A, W, bias, C, M, N, K, blockIdx.y * 64, blockIdx.x * 64);
}

// QKV fused: blockIdx.z selects which of the three GEMMs
__global__ __launch_bounds__(256) void k_gemm_qkv(const float* __restrict__ A,
                                                  const float* __restrict__ W0, const float* __restrict__ W1,
                                                  const float* __restrict__ W2,
                                                  const float* __restrict__ b0, const float* __restrict__ b1,
                                                  const float* __restrict__ b2,
                                                  float* __restrict__ C0, float* __restrict__ C1,
                                                  float* __restrict__ C2,
                                                  int M, int N, int K) {
    const float* W = blockIdx.z == 0 ? W0 : (blockIdx.z == 1 ? W1 : W2);
    const float* B = blockIdx.z == 0 ? b0 : (blockIdx.z == 1 ? b1 : b2);
    float* C = blockIdx.z == 0 ? C0 : (blockIdx.z == 1 ? C1 : C2);
    gemm_body<0>(A, W, B, C, M, N, K, blockIdx.y * 64, blockIdx.x * 64);
}

// ---------------- fused attention: scores+prev -> s, softmax, PV -> ao ----------------
// grid (NB*NH, TOTAL/32), block 256
__global__ __launch_bounds__(256) void k_attn(const float* __restrict__ qm, const float* __restrict__ km,
                                              const float* __restrict__ vm, float* __restrict__ s,
                                              float* __restrict__ ao, int accum) {
    __shared__ float KV[320][18];   // K tile, later V tile
    __shared__ float S[32][321];    // score rows
    int bh = blockIdx.x, b = bh >> 4, h = bh & 15;
    int i0 = blockIdx.y * 32;
    int t = threadIdx.x;
    int wv = t >> 6, lane = t & 63;
    int irow = t >> 3, jg = t & 7;

    // stage K
    for (int idx = t; idx < 320 * 16; idx += 256) {
        int j = idx >> 4, d = idx & 15;
        KV[j][d] = km[(b * TOTAL + j) * DM + h * DK + d];
    }
    // Q row into registers (8 threads share a row -> L1 broadcast)
    float qr[16];
    {
        const float* qp = &qm[(b * TOTAL + i0 + irow) * DM + h * DK];
#pragma unroll
        for (int d = 0; d < 16; d++) qr[d] = qp[d];
    }
    __syncthreads();

    // scores: thread computes S[irow][jg + 8m], m=0..39
    for (int m = 0; m < 40; m++) {
        int j = jg + 8 * m;
        float acc = 0.f;
#pragma unroll
        for (int c = 0; c < 8; c++) {
            float2 kk = *(const float2*)&KV[j][c * 2];
            acc += qr[2 * c] * kk.x + qr[2 * c + 1] * kk.y;
        }
        S[irow][j] = acc * SCALE;
    }
    __syncthreads();

    // add prev, stream accumulated pre-softmax scores to global; stage V (KV free now)
    for (int m = 0; m < 40; m++) {
        int lin = m * 256 + t;
        int i = lin / 320, j = lin - i * 320;
        int g = (bh * TOTAL + i0 + i) * TOTAL + j;
        float sv = S[i][j];
        if (accum) sv += s[g];
        S[i][j] = sv;
        s[g] = sv;
    }
    for (int idx = t; idx < 320 * 16; idx += 256) {
        int j = idx >> 4, d = idx & 15;
        KV[j][d] = vm[(b * TOTAL + j) * DM + h * DK + d];
    }
    __syncthreads();

    // softmax: each wave owns 8 rows; 64 lanes x 5 elements per row
    for (int rr = 0; rr < 8; rr++) {
        int row = wv * 8 + rr;
        float vals[5];
        float mx = -1e30f;
#pragma unroll
        for (int m2 = 0; m2 < 5; m2++) { vals[m2] = S[row][lane + 64 * m2]; mx = fmaxf(mx, vals[m2]); }
#pragma unroll
        for (int off = 32; off > 0; off >>= 1) mx = fmaxf(mx, __shfl_xor(mx, off));
        float sum = 0.f;
#pragma unroll
        for (int m2 = 0; m2 < 5; m2++) { vals[m2] = __expf(vals[m2] - mx); sum += vals[m2]; }
#pragma unroll
        for (int off = 32; off > 0; off >>= 1) sum += __shfl_xor(sum, off);
        float inv = 1.f / sum;
#pragma unroll
        for (int m2 = 0; m2 < 5; m2++) S[row][lane + 64 * m2] = vals[m2] * inv;
    }
    __syncthreads();

    // PV: thread -> (irow, d0=(t&7)*2, d0+1)
    int d0 = (t & 7) * 2;
    float a0 = 0.f, a1 = 0.f;
    for (int j = 0; j < 320; j++) {
        float p = S[irow][j];
        float2 vv = *(const float2*)&KV[j][d0];
        a0 += p * vv.x; a1 += p * vv.y;
    }
    float2 o2 = {a0, a1};
    *(float2*)&ao[(b * TOTAL + i0 + irow) * DM + h * DK + d0] = o2;
}

// ---------------- residual add + LayerNorm (in place on u) ----------------
__global__ void k_add_ln(float* __restrict__ u, const float* __restrict__ o,
                         const float* __restrict__ ls, const float* __restrict__ lb) {
    int row = blockIdx.x, d = threadIdx.x;
    __shared__ float r1[256], r2[256];
    float x = u[row * DM + d] + o[row * DM + d];
    r1[d] = x; r2[d] = x * x; __syncthreads();
    for (int off = 128; off > 0; off >>= 1) {
        if (d < off) { r1[d] += r1[d + off]; r2[d] += r2[d + off]; }
        __syncthreads();
    }
    float m = r1[0] * (1.0f / DM);
    float var = r2[0] * (1.0f / DM) - m * m;
    float rs = rsqrtf(var + EPS);
    u[row * DM + d] = (x - m) * rs * ls[d] + lb[d];
}

// ---------------- transpose u (bc,p,d) -> zzT (bc, d*TOTAL+p) ----------------
__global__ void k_transpose(const float* __restrict__ u, float* __restrict__ zzT) {
    __shared__ float tile[32][33];
    int bc = blockIdx.x, p0 = blockIdx.y * 32, d0 = blockIdx.z * 32;
    int tx = threadIdx.x, ty = threadIdx.y;
    tile[ty][tx] = u[(bc * TOTAL + p0 + ty) * DM + d0 + tx];
    __syncthreads();
    zzT[bc * (DM * TOTAL) + (d0 + ty) * TOTAL + p0 + tx] = tile[tx][ty];
}

// ---------------- head GEMM: acc += zzT(16x81920) @ Wh(81920x96) ----------------
__global__ void k_head(const float* __restrict__ zzT, const float* __restrict__ Wh,
                       float* __restrict__ acc_head) {
    int t0 = blockIdx.x * 16;
    int k0 = blockIdx.y * 1024;
    int tx = threadIdx.x & 15, ty = threadIdx.x >> 4;
    __shared__ float whs[16][17];
    __shared__ float zs[16][17];
    float acc = 0.f;
    for (int kb = 0; kb < 1024; kb += 16) {
        whs[ty][tx] = Wh[(k0 + kb + ty) * TGT + t0 + tx];
        zs[ty][tx] = zzT[ty * (DM * TOTAL) + k0 + kb + tx];
        __syncthreads();
        for (int kk = 0; kk < 16; kk++) acc += zs[ty][kk] * whs[kk][tx];
        __syncthreads();
    }
    atomicAdd(&acc_head[ty * TGT + t0 + tx], acc);
}

// ---------------- final: bias + RevIN denorm -> out ----------------
__global__ void k_final(const float* __restrict__ acc_head, const float* __restrict__ bh,
                        const float* __restrict__ rw, const float* __restrict__ rb,
                        const float* __restrict__ meanv, const float* __restrict__ stdv,
                        float* __restrict__ out) {
    int idx = blockIdx.x * 256 + threadIdx.x;
    if (idx >= NB * TGT) return;
    int bc = idx / TGT, t = idx % TGT, c = bc % C_IN;
    float vv = acc_head[idx] + bh[t];
    vv = (vv - rb[c]) / (rw[c] + EPS * EPS) * stdv[bc] + meanv[bc];
    out[idx] = vv;
}

extern "C" void kernel_launch(void* const* d_in, const int* in_sizes, int n_in,
                              void* d_out, int out_size, void* d_ws, size_t ws_size,
                              hipStream_t stream) {
    const float* z       = (const float*)d_in[0];
    const float* revin_w = (const float*)d_in[1];
    const float* revin_b = (const float*)d_in[2];
    const float* Wf      = (const float*)d_in[3];
    const float* bfv     = (const float*)d_in[4];
    const float* Wc      = (const float*)d_in[5];
    const float* bcv     = (const float*)d_in[6];
    const float* Wpos    = (const float*)d_in[7];
    const float* WQ      = (const float*)d_in[8];
    const float* bQ      = (const float*)d_in[9];
    const float* WK      = (const float*)d_in[10];
    const float* bK      = (const float*)d_in[11];
    const float* WV      = (const float*)d_in[12];
    const float* bV      = (const float*)d_in[13];
    const float* WO      = (const float*)d_in[14];
    const float* bO      = (const float*)d_in[15];
    const float* ln1s    = (const float*)d_in[16];
    const float* ln1b    = (const float*)d_in[17];
    const float* ln2s    = (const float*)d_in[18];
    const float* ln2b    = (const float*)d_in[19];
    const float* F1      = (const float*)d_in[20];
    const float* c1      = (const float*)d_in[21];
    const float* F2      = (const float*)d_in[22];
    const float* c2      = (const float*)d_in[23];
    const float* Wh      = (const float*)d_in[24];
    const float* bh      = (const float*)d_in[25];
    float* out = (float*)d_out;

    float* wsf = (float*)d_ws;
    float* meanv = wsf;  wsf += 16;
    float* stdv  = wsf;  wsf += 16;
    float* zn    = wsf;  wsf += NB * CTX;
    float* u     = wsf;  wsf += NB * TOTAL * DM;
    float* q     = wsf;  wsf += NB * TOTAL * DM;   // also reused for zzT
    float* k     = wsf;  wsf += NB * TOTAL * DM;
    float* v     = wsf;  wsf += NB * TOTAL * DM;
    float* o     = wsf;  wsf += NB * TOTAL * DM;
    float* h     = wsf;  wsf += NB * TOTAL * DFF;  // FFN hidden; also attn-out buffer
    float* s     = wsf;  wsf += NB * NH * TOTAL * TOTAL;   // 104.9 MB residual scores
    float* acc_head = wsf; wsf += NB * TGT;

    const int M = NB * TOTAL;  // 5120

    k_revin<<<NB, 256, 0, stream>>>(z, revin_w, revin_b, zn, meanv, stdv);
    k_embed<<<NB * TOTAL, 256, 0, stream>>>(zn, Wf, bfv, Wc, bcv, Wpos, u);

    for (int l = 0; l < NL; l++) {
        k_gemm_qkv<<<dim3(DM / 64, M / 64, 3), 256, 0, stream>>>(
            u, WQ + l * DM * DM, WK + l * DM * DM, WV + l * DM * DM,
            bQ + l * DM, bK + l * DM, bV + l * DM, q, k, v, M, DM, DM);
        k_attn<<<dim3(NB * NH, TOTAL / 32), 256, 0, stream>>>(q, k, v, s, h, l > 0 ? 1 : 0);
        k_gemm_mfma<0><<<dim3(DM / 64, M / 64), 256, 0, stream>>>(h, WO + l * DM * DM, bO + l * DM, o, M, DM, DM);
        k_add_ln<<<M, 256, 0, stream>>>(u, o, ln1s + l * DM, ln1b + l * DM);
        k_gemm_mfma<1><<<dim3(DFF / 64, M / 64), 256, 0, stream>>>(u, F1 + l * DM * DFF, c1 + l * DFF, h, M, DFF, DM);
        k_gemm_mfma<0><<<dim3(DM / 64, M / 64), 256, 0, stream>>>(h, F2 + l * DFF * DM, c2 + l * DM, o, M, DM, DFF);
        k_add_ln<<<M, 256, 0, stream>>>(u, o, ln2s + l * DM, ln2b + l * DM);
    }

    k_transpose<<<dim3(NB, TOTAL / 32, DM / 32), dim3(32, 32), 0, stream>>>(u, q);
    hipMemsetAsync(acc_head, 0, NB * TGT * sizeof(float), stream);
    k_head<<<dim3(TGT / 16, 80), 256, 0, stream>>>(q, Wh, acc_head);
    k_final<<<(NB * TGT + 255) / 256, 256, 0, stream>>>(acc_head, bh, revin_w, revin_b, meanv, stdv, out);
}

// Round 4
// 920.306 us; speedup vs baseline: 2.3193x; 1.2521x over previous
//
#include <hip/hip_runtime.h>
#include <math.h>

typedef unsigned short ushort;
typedef unsigned int uint;
typedef __attribute__((ext_vector_type(8))) short short8;
typedef __attribute__((ext_vector_type(4))) float f32x4;

constexpr int BS = 2, C_IN = 8, CTX = 1024, TGT = 96;
constexpr int DM = 256, NH = 16, DFF = 1024, NL = 4;
constexpr int NF = 256, TOTAL = 320;
constexpr int NB = 16;   // BS * C_IN sequences
constexpr int DK = 16;
constexpr float EPS = 1e-5f;
constexpr float SCALE = 0.25f;  // DK^-0.5

__device__ __forceinline__ ushort f2b(float x) {
    uint u = __float_as_uint(x);
    u += 0x7fff + ((u >> 16) & 1);   // round-to-nearest-even
    return (ushort)(u >> 16);
}

// ---------------- RevIN ----------------
__global__ void k_revin(const float* __restrict__ z, const float* __restrict__ rw,
                        const float* __restrict__ rb, float* __restrict__ zn,
                        float* __restrict__ meanv, float* __restrict__ stdv) {
    int bc = blockIdx.x, t = threadIdx.x;
    __shared__ float r1[256], r2[256];
    float s1 = 0.f, s2 = 0.f;
    for (int i = t; i < CTX; i += 256) {
        float x = z[bc * CTX + i];
        s1 += x; s2 += x * x;
    }
    r1[t] = s1; r2[t] = s2; __syncthreads();
    for (int off = 128; off > 0; off >>= 1) {
        if (t < off) { r1[t] += r1[t + off]; r2[t] += r2[t + off]; }
        __syncthreads();
    }
    float m = r1[0] * (1.0f / CTX);
    float var = r2[0] * (1.0f / CTX) - m * m;
    float sd = sqrtf(var + EPS);
    float w = rw[bc % C_IN], b = rb[bc % C_IN];
    float inv = 1.0f / sd;
    for (int i = t; i < CTX; i += 256) {
        float x = z[bc * CTX + i];
        zn[bc * CTX + i] = (x - m) * inv * w + b;
    }
    if (t == 0) { meanv[bc] = m; stdv[bc] = sd; }
}

// ---------------- dual-scale patch embed + positional ----------------
__global__ void k_embed(const float* __restrict__ zn, const float* __restrict__ Wf,
                        const float* __restrict__ bfv, const float* __restrict__ Wc,
                        const float* __restrict__ bcv, const float* __restrict__ Wpos,
                        float* __restrict__ u) {
    int bc = blockIdx.x / TOTAL, p = blockIdx.x % TOTAL, d = threadIdx.x;
    float acc;
    if (p < NF) {
        acc = bfv[d];
        int base = p * 4;
        for (int i = 0; i < 8; i++) {
            int idx = min(base + i, CTX - 1);
            acc += zn[bc * CTX + idx] * Wf[i * DM + d];
        }
    } else {
        int pc = p - NF;
        acc = bcv[d];
        int base = pc * 16;
        for (int i = 0; i < 32; i++) {
            int idx = min(base + i, CTX - 1);
            acc += zn[bc * CTX + idx] * Wc[i * DM + d];
        }
    }
    acc += Wpos[p * DM + d];
    u[(bc * TOTAL + p) * DM + d] = acc;
}

// ---------------- bf16 MFMA GEMM body ----------------
template <int GELU>
__device__ __forceinline__ void gemm_body(const float* __restrict__ A,
                                          const float* __restrict__ W,
                                          const float* __restrict__ bias,
                                          float* __restrict__ C,
                                          int M, int N, int K,
                                          int m0, int n0) {
    __shared__ ushort Asb[64][40];
    __shared__ ushort Bsb[64][40];
    int tid = threadIdx.x;
    int wave = tid >> 6, lane = tid & 63;
    int quad = lane >> 4, l16 = lane & 15;

    f32x4 acc[4];
    for (int nt = 0; nt < 4; nt++) acc[nt] = (f32x4){0.f, 0.f, 0.f, 0.f};

    for (int k0 = 0; k0 < K; k0 += 32) {
        {
            int row = tid >> 2, kc = (tid & 3) * 8;
            const float* ga = &A[(m0 + row) * K + k0 + kc];
            union { short8 v; ushort s[8]; } tmp;
#pragma unroll
            for (int j = 0; j < 8; j++) tmp.s[j] = f2b(ga[j]);
            *(short8*)&Asb[row][kc] = tmp.v;
        }
        {
            int n = tid & 63, kg = (tid >> 6) * 8;
            union { short8 v; ushort s[8]; } tmp;
#pragma unroll
            for (int j = 0; j < 8; j++) tmp.s[j] = f2b(W[(k0 + kg + j) * N + n0 + n]);
            *(short8*)&Bsb[n][kg] = tmp.v;
        }
        __syncthreads();
        short8 af = *(const short8*)&Asb[wave * 16 + l16][quad * 8];
#pragma unroll
        for (int nt = 0; nt < 4; nt++) {
            short8 bf = *(const short8*)&Bsb[nt * 16 + l16][quad * 8];
            acc[nt] = __builtin_amdgcn_mfma_f32_16x16x32_bf16(af, bf, acc[nt], 0, 0, 0);
        }
        __syncthreads();
    }
#pragma unroll
    for (int nt = 0; nt < 4; nt++) {
        int col = n0 + nt * 16 + l16;
        float bi = bias[col];
#pragma unroll
        for (int r = 0; r < 4; r++) {
            int row = m0 + wave * 16 + quad * 4 + r;
            float vv = acc[nt][r] + bi;
            if (GELU) vv = vv * 0.5f * (1.0f + erff(vv * 0.70710678118f));
            C[row * N + col] = vv;
        }
    }
}

template <int GELU>
__global__ __launch_bounds__(256) void k_gemm_mfma(const float* __restrict__ A,
                                                   const float* __restrict__ W,
                                                   const float* __restrict__ bias,
                                                   float* __restrict__ C,
                                                   int M, int N, int K) {
    gemm_body<GELU>(A, W, bias, C, M, N, K, blockIdx.y * 64, blockIdx.x * 64);
}

__global__ __launch_bounds__(256) void k_gemm_qkv(const float* __restrict__ A,
                                                  const float* __restrict__ W0, const float* __restrict__ W1,
                                                  const float* __restrict__ W2,
                                                  const float* __restrict__ b0, const float* __restrict__ b1,
                                                  const float* __restrict__ b2,
                                                  float* __restrict__ C0, float* __restrict__ C1,
                                                  float* __restrict__ C2,
                                                  int M, int N, int K) {
    const float* W = blockIdx.z == 0 ? W0 : (blockIdx.z == 1 ? W1 : W2);
    const float* B = blockIdx.z == 0 ? b0 : (blockIdx.z == 1 ? b1 : b2);
    float* C = blockIdx.z == 0 ? C0 : (blockIdx.z == 1 ? C1 : C2);
    gemm_body<0>(A, W, B, C, M, N, K, blockIdx.y * 64, blockIdx.x * 64);
}

// ---------------- MFMA fused attention ----------------
// grid (NB*NH, TOTAL/64), block 256 (4 waves x 16 rows).
// LDS layout (ushort idx):
//   K frag region  [0 .. 10240)       : slot ((jt*4+quad)*16+n)*8+kk, jt<20 (16-col tiles), quads 2,3 zero
//   P region       [0 .. 20992)       : wave w at w*5248, row*328 + col   (overlaps K; written after barrier 2)
//   Vt frag region [20992 .. 26112)   : slot ((jt*4+quad)*16+d)*8+jj, jt<10 (32-k tiles)
__global__ __launch_bounds__(256) void k_attn(const float* __restrict__ qm, const float* __restrict__ km,
                                              const float* __restrict__ vm, float* __restrict__ s,
                                              float* __restrict__ ao, int accum) {
    __shared__ ushort sh[26112];
    uint* sh32 = (uint*)sh;
    constexpr int VT32 = 10496;   // uint index of Vt base (ushort 20992)

    int bh = blockIdx.x, b = bh >> 4, h = bh & 15;
    int i0 = blockIdx.y * 64;
    int t = threadIdx.x, wave = t >> 6, lane = t & 63, quad = lane >> 4, l16 = lane & 15;

    // ---- stage K (bf16, frag order, zero-padded k 16->32); uint-packed writes ----
    for (int idx = t; idx < 320 * 16; idx += 256) {
        int j = idx >> 4, c = idx & 15;          // c = uint within row, k = 2c
        uint val = 0;
        if (c < 8) {
            const float* kp = &km[(b * TOTAL + j) * DM + h * DK + c * 2];
            val = (uint)f2b(kp[0]) | ((uint)f2b(kp[1]) << 16);
        }
        int kq = c >> 2;                          // quad = k>>3 = c>>2
        sh32[(((j >> 4) * 4 + kq) * 16 + (j & 15)) * 4 + (c & 3)] = val;
    }
    // ---- stage V^T (bf16, frag order for PV B-operand) ----
    for (int idx = t; idx < 160 * 16; idx += 256) {
        int j2 = idx >> 4, d = idx & 15;
        int j = j2 * 2;
        float v0 = vm[(b * TOTAL + j) * DM + h * DK + d];
        float v1 = vm[(b * TOTAL + j + 1) * DM + h * DK + d];
        uint val = (uint)f2b(v0) | ((uint)f2b(v1) << 16);
        int jt = j >> 5, r = j & 31, vq = r >> 3, jj = r & 7;
        sh32[VT32 + ((jt * 4 + vq) * 16 + d) * 4 + (jj >> 1)] = val;
    }
    // ---- Q A-frag: k = quad*8+jj, real for quad<2; scale folded in ----
    union { short8 v; ushort u[8]; } qf;
    if (quad < 2) {
        const float* qp = &qm[(b * TOTAL + i0 + wave * 16 + l16) * DM + h * DK + quad * 8];
#pragma unroll
        for (int jj = 0; jj < 8; jj++) qf.u[jj] = f2b(qp[jj] * SCALE);
    } else {
#pragma unroll
        for (int jj = 0; jj < 8; jj++) qf.u[jj] = 0;
    }
    __syncthreads();

    // ---- QK^T: 20 col-tiles, one MFMA each ----
    f32x4 acc[20];
#pragma unroll
    for (int nt = 0; nt < 20; nt++) {
        short8 kf = *(const short8*)&sh[((nt * 4 + quad) * 16 + l16) * 8];
        acc[nt] = __builtin_amdgcn_mfma_f32_16x16x32_bf16(qf.v, kf, (f32x4){0.f, 0.f, 0.f, 0.f}, 0, 0, 0);
    }
    __syncthreads();   // K region dead after this; P writes may begin

    // ---- prev add + s writeback (registers <-> global, coalesced) ----
    int rowbase = bh * TOTAL + i0 + wave * 16 + quad * 4;
#pragma unroll
    for (int r = 0; r < 4; r++) {
        int gbase = (rowbase + r) * TOTAL + l16;
        if (accum) {
#pragma unroll
            for (int nt = 0; nt < 20; nt++) acc[nt][r] += s[gbase + nt * 16];
        }
#pragma unroll
        for (int nt = 0; nt < 20; nt++) s[gbase + nt * 16] = acc[nt][r];
    }

    // ---- softmax in registers (16-lane shuffle reductions), write P (bf16) to wave-private LDS ----
#pragma unroll
    for (int r = 0; r < 4; r++) {
        float mx = -1e30f;
#pragma unroll
        for (int nt = 0; nt < 20; nt++) mx = fmaxf(mx, acc[nt][r]);
        mx = fmaxf(mx, __shfl_xor(mx, 1));
        mx = fmaxf(mx, __shfl_xor(mx, 2));
        mx = fmaxf(mx, __shfl_xor(mx, 4));
        mx = fmaxf(mx, __shfl_xor(mx, 8));
        float sum = 0.f;
#pragma unroll
        for (int nt = 0; nt < 20; nt++) { acc[nt][r] = __expf(acc[nt][r] - mx); sum += acc[nt][r]; }
        sum += __shfl_xor(sum, 1);
        sum += __shfl_xor(sum, 2);
        sum += __shfl_xor(sum, 4);
        sum += __shfl_xor(sum, 8);
        float inv = 1.f / sum;
        int prow = wave * 5248 + (quad * 4 + r) * 328 + l16;
#pragma unroll
        for (int nt = 0; nt < 20; nt++) sh[prow + nt * 16] = f2b(acc[nt][r] * inv);
    }

    // ---- PV: 10 MFMAs, A = P (wave-private LDS), B = Vt frags ----
    f32x4 oacc = (f32x4){0.f, 0.f, 0.f, 0.f};
#pragma unroll
    for (int jt = 0; jt < 10; jt++) {
        short8 pf = *(const short8*)&sh[wave * 5248 + l16 * 328 + jt * 32 + quad * 8];
        short8 vf = *(const short8*)&sh[20992 + ((jt * 4 + quad) * 16 + l16) * 8];
        oacc = __builtin_amdgcn_mfma_f32_16x16x32_bf16(pf, vf, oacc, 0, 0, 0);
    }
#pragma unroll
    for (int r = 0; r < 4; r++)
        ao[(b * TOTAL + i0 + wave * 16 + quad * 4 + r) * DM + h * DK + l16] = oacc[r];
}

// ---------------- residual add + LayerNorm (in place on u) ----------------
__global__ void k_add_ln(float* __restrict__ u, const float* __restrict__ o,
                         const float* __restrict__ ls, const float* __restrict__ lb) {
    int row = blockIdx.x, d = threadIdx.x;
    __shared__ float r1[256], r2[256];
    float x = u[row * DM + d] + o[row * DM + d];
    r1[d] = x; r2[d] = x * x; __syncthreads();
    for (int off = 128; off > 0; off >>= 1) {
        if (d < off) { r1[d] += r1[d + off]; r2[d] += r2[d + off]; }
        __syncthreads();
    }
    float m = r1[0] * (1.0f / DM);
    float var = r2[0] * (1.0f / DM) - m * m;
    float rs = rsqrtf(var + EPS);
    u[row * DM + d] = (x - m) * rs * ls[d] + lb[d];
}

// ---------------- transpose u (bc,p,d) -> zzT (bc, d*TOTAL+p) ----------------
__global__ void k_transpose(const float* __restrict__ u, float* __restrict__ zzT) {
    __shared__ float tile[32][33];
    int bc = blockIdx.x, p0 = blockIdx.y * 32, d0 = blockIdx.z * 32;
    int tx = threadIdx.x, ty = threadIdx.y;
    tile[ty][tx] = u[(bc * TOTAL + p0 + ty) * DM + d0 + tx];
    __syncthreads();
    zzT[bc * (DM * TOTAL) + (d0 + ty) * TOTAL + p0 + tx] = tile[tx][ty];
}

// ---------------- head GEMM ----------------
__global__ void k_head(const float* __restrict__ zzT, const float* __restrict__ Wh,
                       float* __restrict__ acc_head) {
    int t0 = blockIdx.x * 16;
    int k0 = blockIdx.y * 1024;
    int tx = threadIdx.x & 15, ty = threadIdx.x >> 4;
    __shared__ float whs[16][17];
    __shared__ float zs[16][17];
    float acc = 0.f;
    for (int kb = 0; kb < 1024; kb += 16) {
        whs[ty][tx] = Wh[(k0 + kb + ty) * TGT + t0 + tx];
        zs[ty][tx] = zzT[ty * (DM * TOTAL) + k0 + kb + tx];
        __syncthreads();
        for (int kk = 0; kk < 16; kk++) acc += zs[ty][kk] * whs[kk][tx];
        __syncthreads();
    }
    atomicAdd(&acc_head[ty * TGT + t0 + tx], acc);
}

// ---------------- final: bias + RevIN denorm -> out ----------------
__global__ void k_final(const float* __restrict__ acc_head, const float* __restrict__ bh,
                        const float* __restrict__ rw, const float* __restrict__ rb,
                        const float* __restrict__ meanv, const float* __restrict__ stdv,
                        float* __restrict__ out) {
    int idx = blockIdx.x * 256 + threadIdx.x;
    if (idx >= NB * TGT) return;
    int bc = idx / TGT, t = idx % TGT, c = bc % C_IN;
    float vv = acc_head[idx] + bh[t];
    vv = (vv - rb[c]) / (rw[c] + EPS * EPS) * stdv[bc] + meanv[bc];
    out[idx] = vv;
}

extern "C" void kernel_launch(void* const* d_in, const int* in_sizes, int n_in,
                              void* d_out, int out_size, void* d_ws, size_t ws_size,
                              hipStream_t stream) {
    const float* z       = (const float*)d_in[0];
    const float* revin_w = (const float*)d_in[1];
    const float* revin_b = (const float*)d_in[2];
    const float* Wf      = (const float*)d_in[3];
    const float* bfv     = (const float*)d_in[4];
    const float* Wc      = (const float*)d_in[5];
    const float* bcv     = (const float*)d_in[6];
    const float* Wpos    = (const float*)d_in[7];
    const float* WQ      = (const float*)d_in[8];
    const float* bQ      = (const float*)d_in[9];
    const float* WK      = (const float*)d_in[10];
    const float* bK      = (const float*)d_in[11];
    const float* WV      = (const float*)d_in[12];
    const float* bV      = (const float*)d_in[13];
    const float* WO      = (const float*)d_in[14];
    const float* bO      = (const float*)d_in[15];
    const float* ln1s    = (const float*)d_in[16];
    const float* ln1b    = (const float*)d_in[17];
    const float* ln2s    = (const float*)d_in[18];
    const float* ln2b    = (const float*)d_in[19];
    const float* F1      = (const float*)d_in[20];
    const float* c1      = (const float*)d_in[21];
    const float* F2      = (const float*)d_in[22];
    const float* c2      = (const float*)d_in[23];
    const float* Wh      = (const float*)d_in[24];
    const float* bh      = (const float*)d_in[25];
    float* out = (float*)d_out;

    float* wsf = (float*)d_ws;
    float* meanv = wsf;  wsf += 16;
    float* stdv  = wsf;  wsf += 16;
    float* zn    = wsf;  wsf += NB * CTX;
    float* u     = wsf;  wsf += NB * TOTAL * DM;
    float* q     = wsf;  wsf += NB * TOTAL * DM;   // also reused for zzT
    float* k     = wsf;  wsf += NB * TOTAL * DM;
    float* v     = wsf;  wsf += NB * TOTAL * DM;
    float* o     = wsf;  wsf += NB * TOTAL * DM;
    float* h     = wsf;  wsf += NB * TOTAL * DFF;  // FFN hidden; also attn-out buffer
    float* s     = wsf;  wsf += NB * NH * TOTAL * TOTAL;   // 104.9 MB residual scores
    float* acc_head = wsf; wsf += NB * TGT;

    const int M = NB * TOTAL;  // 5120

    k_revin<<<NB, 256, 0, stream>>>(z, revin_w, revin_b, zn, meanv, stdv);
    k_embed<<<NB * TOTAL, 256, 0, stream>>>(zn, Wf, bfv, Wc, bcv, Wpos, u);

    for (int l = 0; l < NL; l++) {
        k_gemm_qkv<<<dim3(DM / 64, M / 64, 3), 256, 0, stream>>>(
            u, WQ + l * DM * DM, WK + l * DM * DM, WV + l * DM * DM,
            bQ + l * DM, bK + l * DM, bV + l * DM, q, k, v, M, DM, DM);
        k_attn<<<dim3(NB * NH, TOTAL / 64), 256, 0, stream>>>(q, k, v, s, h, l > 0 ? 1 : 0);
        k_gemm_mfma<0><<<dim3(DM / 64, M / 64), 256, 0, stream>>>(h, WO + l * DM * DM, bO + l * DM, o, M, DM, DM);
        k_add_ln<<<M, 256, 0, stream>>>(u, o, ln1s + l * DM, ln1b + l * DM);
        k_gemm_mfma<1><<<dim3(DFF / 64, M / 64), 256, 0, stream>>>(u, F1 + l * DM * DFF, c1 + l * DFF, h, M, DFF, DM);
        k_gemm_mfma<0><<<dim3(DM / 64, M / 64), 256, 0, stream>>>(h, F2 + l * DFF * DM, c2 + l * DM, o, M, DM, DFF);
        k_add_ln<<<M, 256, 0, stream>>>(u, o, ln2s + l * DM, ln2b + l * DM);
    }

    k_transpose<<<dim3(NB, TOTAL / 32, DM / 32), dim3(32, 32), 0, stream>>>(u, q);
    hipMemsetAsync(acc_head, 0, NB * TGT * sizeof(float), stream);
    k_head<<<dim3(TGT / 16, 80), 256, 0, stream>>>(q, Wh, acc_head);
    k_final<<<(NB * TGT + 255) / 256, 256, 0, stream>>>(acc_head, bh, revin_w, revin_b, meanv, stdv, out);
}

// Round 5
// 648.800 us; speedup vs baseline: 3.2899x; 1.4185x over previous
//
#include <hip/hip_runtime.h>
#include <math.h>

typedef unsigned short ushort;
typedef unsigned int uint;
typedef __attribute__((ext_vector_type(8))) short short8;
typedef __attribute__((ext_vector_type(4))) float f32x4;

constexpr int BS = 2, C_IN = 8, CTX = 1024, TGT = 96;
constexpr int DM = 256, NH = 16, DFF = 1024, NL = 4;
constexpr int NF = 256, TOTAL = 320;
constexpr int NB = 16;
constexpr int DK = 16;
constexpr float EPS = 1e-5f;
constexpr float SCALE = 0.25f;

__device__ __forceinline__ ushort f2b(float x) {
    uint u = __float_as_uint(x);
    u += 0x7fff + ((u >> 16) & 1);
    return (ushort)(u >> 16);
}
__device__ __forceinline__ float bu2f(ushort x) { return __uint_as_float(((uint)x) << 16); }
__device__ __forceinline__ float lo2f(uint p) { return __uint_as_float(p << 16); }
__device__ __forceinline__ float hi2f(uint p) { return __uint_as_float(p & 0xffff0000u); }
__device__ __forceinline__ uint pack2(float a, float b) { return (uint)f2b(a) | ((uint)f2b(b) << 16); }

// ---------------- weight convert + transpose: src fp32 (R x C, L layers) -> dst bf16 (C x R) ----------------
__global__ void k_convt(const float* __restrict__ src, ushort* __restrict__ dst,
                        int R, int C, int sls, int dls) {
    __shared__ ushort tile[32][33];
    src += (size_t)blockIdx.z * sls;
    dst += (size_t)blockIdx.z * dls;
    int c0 = blockIdx.x * 32, r0 = blockIdx.y * 32;
    int tx = threadIdx.x, ty = threadIdx.y;
    tile[ty][tx] = f2b(src[(r0 + ty) * C + c0 + tx]);
    __syncthreads();
    dst[(c0 + ty) * R + r0 + tx] = tile[tx][ty];
}

// ---------------- RevIN ----------------
__global__ void k_revin(const float* __restrict__ z, const float* __restrict__ rw,
                        const float* __restrict__ rb, float* __restrict__ zn,
                        float* __restrict__ meanv, float* __restrict__ stdv) {
    int bc = blockIdx.x, t = threadIdx.x;
    __shared__ float r1[256], r2[256];
    float s1 = 0.f, s2 = 0.f;
    for (int i = t; i < CTX; i += 256) {
        float x = z[bc * CTX + i];
        s1 += x; s2 += x * x;
    }
    r1[t] = s1; r2[t] = s2; __syncthreads();
    for (int off = 128; off > 0; off >>= 1) {
        if (t < off) { r1[t] += r1[t + off]; r2[t] += r2[t + off]; }
        __syncthreads();
    }
    float m = r1[0] * (1.0f / CTX);
    float var = r2[0] * (1.0f / CTX) - m * m;
    float sd = sqrtf(var + EPS);
    float w = rw[bc % C_IN], b = rb[bc % C_IN];
    float inv = 1.0f / sd;
    for (int i = t; i < CTX; i += 256) {
        float x = z[bc * CTX + i];
        zn[bc * CTX + i] = (x - m) * inv * w + b;
    }
    if (t == 0) { meanv[bc] = m; stdv[bc] = sd; }
}

// ---------------- dual-scale patch embed + positional -> bf16 u ----------------
__global__ void k_embed(const float* __restrict__ zn, const float* __restrict__ Wf,
                        const float* __restrict__ bfv, const float* __restrict__ Wc,
                        const float* __restrict__ bcv, const float* __restrict__ Wpos,
                        ushort* __restrict__ u) {
    int bc = blockIdx.x / TOTAL, p = blockIdx.x % TOTAL, d = threadIdx.x;
    float acc;
    if (p < NF) {
        acc = bfv[d];
        int base = p * 4;
        for (int i = 0; i < 8; i++) {
            int idx = min(base + i, CTX - 1);
            acc += zn[bc * CTX + idx] * Wf[i * DM + d];
        }
    } else {
        int pc = p - NF;
        acc = bcv[d];
        int base = pc * 16;
        for (int i = 0; i < 32; i++) {
            int idx = min(base + i, CTX - 1);
            acc += zn[bc * CTX + idx] * Wc[i * DM + d];
        }
    }
    acc += Wpos[p * DM + d];
    u[(bc * TOTAL + p) * DM + d] = f2b(acc);
}

// ---------------- bf16 MFMA GEMM: C = A(MxK) @ Wt^T + bias; Wt is (N x K) bf16 ----------------
// 64x64 tile, 4 waves. QKV=1: N=768, output split across 3 MxDM buffers at C.
template <int GELU, int QKV>
__global__ __launch_bounds__(256) void k_gemm_mfma(const ushort* __restrict__ A,
                                                   const ushort* __restrict__ Wt,
                                                   const float* __restrict__ b0,
                                                   const float* __restrict__ b1,
                                                   const float* __restrict__ b2,
                                                   ushort* __restrict__ C,
                                                   int M, int N, int K) {
    __shared__ ushort As[64][40];
    __shared__ ushort Bs[64][40];
    int tid = threadIdx.x;
    int wave = tid >> 6, lane = tid & 63;
    int quad = lane >> 4, l16 = lane & 15;
    int m0 = blockIdx.y * 64, n0 = blockIdx.x * 64;

    f32x4 acc[4];
#pragma unroll
    for (int nt = 0; nt < 4; nt++) acc[nt] = (f32x4){0.f, 0.f, 0.f, 0.f};

    int row = tid >> 2, kc = (tid & 3) * 8;
    for (int k0 = 0; k0 < K; k0 += 32) {
        *(short8*)&As[row][kc] = *(const short8*)&A[(m0 + row) * K + k0 + kc];
        *(short8*)&Bs[row][kc] = *(const short8*)&Wt[(n0 + row) * K + k0 + kc];
        __syncthreads();
        short8 af = *(const short8*)&As[wave * 16 + l16][quad * 8];
#pragma unroll
        for (int nt = 0; nt < 4; nt++) {
            short8 bf = *(const short8*)&Bs[nt * 16 + l16][quad * 8];
            acc[nt] = __builtin_amdgcn_mfma_f32_16x16x32_bf16(af, bf, acc[nt], 0, 0, 0);
        }
        __syncthreads();
    }
#pragma unroll
    for (int nt = 0; nt < 4; nt++) {
        int col = n0 + nt * 16 + l16;
        float bi;
        if (QKV) {
            int bs = (n0 + nt * 16) >> 8;
            const float* bp = bs == 0 ? b0 : (bs == 1 ? b1 : b2);
            bi = bp[col & 255];
        } else {
            bi = b0[col];
        }
#pragma unroll
        for (int r = 0; r < 4; r++) {
            int rowm = m0 + wave * 16 + quad * 4 + r;
            float vv = acc[nt][r] + bi;
            if (GELU) vv = vv * 0.5f * (1.0f + erff(vv * 0.70710678118f));
            if (QKV) C[(col >> 8) * (M * DM) + rowm * DM + (col & 255)] = f2b(vv);
            else C[rowm * N + col] = f2b(vv);
        }
    }
}

// ---------------- MFMA fused attention, bf16 I/O, packed-bf16 s in register layout ----------------
// grid (NB*NH, 5), block 256. s chunk index: ((bh*5+iblk)*10 + c)*256 + t  (uint4 = 8 bf16)
__global__ __launch_bounds__(256) void k_attn(const ushort* __restrict__ qm, const ushort* __restrict__ km,
                                              const ushort* __restrict__ vm, uint4* __restrict__ sp,
                                              ushort* __restrict__ ao, int accum) {
    __shared__ ushort sh[26112];
    uint* sh32 = (uint*)sh;
    constexpr int VT32 = 10496;

    int bh = blockIdx.x, b = bh >> 4, h = bh & 15;
    int i0 = blockIdx.y * 64;
    int t = threadIdx.x, wave = t >> 6, lane = t & 63, quad = lane >> 4, l16 = lane & 15;

    // stage K (frag order, zero-pad k 16->32)
    for (int idx = t; idx < 320 * 16; idx += 256) {
        int j = idx >> 4, c = idx & 15;
        uint val = 0;
        if (c < 8) val = *(const uint*)&km[(b * TOTAL + j) * DM + h * DK + c * 2];
        int kq = c >> 2;
        sh32[(((j >> 4) * 4 + kq) * 16 + (j & 15)) * 4 + (c & 3)] = val;
    }
    // stage V^T (frag order for PV B-operand)
    for (int idx = t; idx < 160 * 16; idx += 256) {
        int j2 = idx >> 4, d = idx & 15;
        int j = j2 * 2;
        uint val = (uint)vm[(b * TOTAL + j) * DM + h * DK + d] |
                   ((uint)vm[(b * TOTAL + j + 1) * DM + h * DK + d] << 16);
        int jt = j >> 5, r = j & 31, vq = r >> 3, jj = r & 7;
        sh32[VT32 + ((jt * 4 + vq) * 16 + d) * 4 + (jj >> 1)] = val;
    }
    // Q A-frag
    short8 qf;
    if (quad < 2) qf = *(const short8*)&qm[(b * TOTAL + i0 + wave * 16 + l16) * DM + h * DK + quad * 8];
    else qf = (short8){0, 0, 0, 0, 0, 0, 0, 0};
    __syncthreads();

    // QK^T
    f32x4 acc[20];
#pragma unroll
    for (int nt = 0; nt < 20; nt++) {
        short8 kf = *(const short8*)&sh[((nt * 4 + quad) * 16 + l16) * 8];
        acc[nt] = __builtin_amdgcn_mfma_f32_16x16x32_bf16(qf, kf, (f32x4){0.f, 0.f, 0.f, 0.f}, 0, 0, 0);
    }
    __syncthreads();   // K region dead; P region may be written

    // scale + prev add + s writeback (vectorized, coalesced, bf16)
    int cb = (bh * 5 + (int)blockIdx.y) * 10 * 256 + t;
#pragma unroll
    for (int c = 0; c < 10; c++) {
        float e[8];
#pragma unroll
        for (int j = 0; j < 8; j++) e[j] = acc[2 * c + (j >> 2)][j & 3] * SCALE;
        if (accum) {
            uint4 pv = sp[cb + c * 256];
            e[0] += lo2f(pv.x); e[1] += hi2f(pv.x); e[2] += lo2f(pv.y); e[3] += hi2f(pv.y);
            e[4] += lo2f(pv.z); e[5] += hi2f(pv.z); e[6] += lo2f(pv.w); e[7] += hi2f(pv.w);
        }
        uint4 ov;
        ov.x = pack2(e[0], e[1]); ov.y = pack2(e[2], e[3]);
        ov.z = pack2(e[4], e[5]); ov.w = pack2(e[6], e[7]);
        sp[cb + c * 256] = ov;
#pragma unroll
        for (int j = 0; j < 8; j++) acc[2 * c + (j >> 2)][j & 3] = e[j];
    }

    // softmax in registers, write P (bf16) to wave-private LDS
#pragma unroll
    for (int r = 0; r < 4; r++) {
        float mx = -1e30f;
#pragma unroll
        for (int nt = 0; nt < 20; nt++) mx = fmaxf(mx, acc[nt][r]);
        mx = fmaxf(mx, __shfl_xor(mx, 1));
        mx = fmaxf(mx, __shfl_xor(mx, 2));
        mx = fmaxf(mx, __shfl_xor(mx, 4));
        mx = fmaxf(mx, __shfl_xor(mx, 8));
        float sum = 0.f;
#pragma unroll
        for (int nt = 0; nt < 20; nt++) { acc[nt][r] = __expf(acc[nt][r] - mx); sum += acc[nt][r]; }
        sum += __shfl_xor(sum, 1);
        sum += __shfl_xor(sum, 2);
        sum += __shfl_xor(sum, 4);
        sum += __shfl_xor(sum, 8);
        float inv = 1.f / sum;
        int prow = wave * 5248 + (quad * 4 + r) * 328 + l16;
#pragma unroll
        for (int nt = 0; nt < 20; nt++) sh[prow + nt * 16] = f2b(acc[nt][r] * inv);
    }

    // PV
    f32x4 oacc = (f32x4){0.f, 0.f, 0.f, 0.f};
#pragma unroll
    for (int jt = 0; jt < 10; jt++) {
        short8 pf = *(const short8*)&sh[wave * 5248 + l16 * 328 + jt * 32 + quad * 8];
        short8 vf = *(const short8*)&sh[20992 + ((jt * 4 + quad) * 16 + l16) * 8];
        oacc = __builtin_amdgcn_mfma_f32_16x16x32_bf16(pf, vf, oacc, 0, 0, 0);
    }
#pragma unroll
    for (int r = 0; r < 4; r++)
        ao[(b * TOTAL + i0 + wave * 16 + quad * 4 + r) * DM + h * DK + l16] = f2b(oacc[r]);
}

// ---------------- residual add + LayerNorm (bf16 in/out, fp32 math) ----------------
__global__ void k_add_ln(ushort* __restrict__ u, const ushort* __restrict__ o,
                         const float* __restrict__ ls, const float* __restrict__ lb) {
    int row = blockIdx.x, d = threadIdx.x;
    __shared__ float r1[256], r2[256];
    float x = bu2f(u[row * DM + d]) + bu2f(o[row * DM + d]);
    r1[d] = x; r2[d] = x * x; __syncthreads();
    for (int off = 128; off > 0; off >>= 1) {
        if (d < off) { r1[d] += r1[d + off]; r2[d] += r2[d + off]; }
        __syncthreads();
    }
    float m = r1[0] * (1.0f / DM);
    float var = r2[0] * (1.0f / DM) - m * m;
    float rs = rsqrtf(var + EPS);
    u[row * DM + d] = f2b((x - m) * rs * ls[d] + lb[d]);
}

// ---------------- transpose u (bc,p,d) -> zzT (bc, d*TOTAL+p), bf16 ----------------
__global__ void k_transpose(const ushort* __restrict__ u, ushort* __restrict__ zzT) {
    __shared__ ushort tile[32][34];
    int bc = blockIdx.x, p0 = blockIdx.y * 32, d0 = blockIdx.z * 32;
    int tx = threadIdx.x, ty = threadIdx.y;
    tile[ty][tx] = u[(bc * TOTAL + p0 + ty) * DM + d0 + tx];
    __syncthreads();
    zzT[bc * (DM * TOTAL) + (d0 + ty) * TOTAL + p0 + tx] = tile[tx][ty];
}

// ---------------- head GEMM: acc += zzT(16x81920 bf16) @ Wh(81920x96 fp32) ----------------
__global__ void k_head(const ushort* __restrict__ zzT, const float* __restrict__ Wh,
                       float* __restrict__ acc_head) {
    int t0 = blockIdx.x * 16;
    int k0 = blockIdx.y * 1024;
    int tx = threadIdx.x & 15, ty = threadIdx.x >> 4;
    __shared__ float whs[16][17];
    __shared__ float zs[16][17];
    float acc = 0.f;
    for (int kb = 0; kb < 1024; kb += 16) {
        whs[ty][tx] = Wh[(k0 + kb + ty) * TGT + t0 + tx];
        zs[ty][tx] = bu2f(zzT[ty * (DM * TOTAL) + k0 + kb + tx]);
        __syncthreads();
        for (int kk = 0; kk < 16; kk++) acc += zs[ty][kk] * whs[kk][tx];
        __syncthreads();
    }
    atomicAdd(&acc_head[ty * TGT + t0 + tx], acc);
}

// ---------------- final ----------------
__global__ void k_final(const float* __restrict__ acc_head, const float* __restrict__ bh,
                        const float* __restrict__ rw, const float* __restrict__ rb,
                        const float* __restrict__ meanv, const float* __restrict__ stdv,
                        float* __restrict__ out) {
    int idx = blockIdx.x * 256 + threadIdx.x;
    if (idx >= NB * TGT) return;
    int bc = idx / TGT, t = idx % TGT, c = bc % C_IN;
    float vv = acc_head[idx] + bh[t];
    vv = (vv - rb[c]) / (rw[c] + EPS * EPS) * stdv[bc] + meanv[bc];
    out[idx] = vv;
}

extern "C" void kernel_launch(void* const* d_in, const int* in_sizes, int n_in,
                              void* d_out, int out_size, void* d_ws, size_t ws_size,
                              hipStream_t stream) {
    const float* z       = (const float*)d_in[0];
    const float* revin_w = (const float*)d_in[1];
    const float* revin_b = (const float*)d_in[2];
    const float* Wf      = (const float*)d_in[3];
    const float* bfv     = (const float*)d_in[4];
    const float* Wc      = (const float*)d_in[5];
    const float* bcv     = (const float*)d_in[6];
    const float* Wpos    = (const float*)d_in[7];
    const float* WQ      = (const float*)d_in[8];
    const float* bQ      = (const float*)d_in[9];
    const float* WK      = (const float*)d_in[10];
    const float* bK      = (const float*)d_in[11];
    const float* WV      = (const float*)d_in[12];
    const float* bV      = (const float*)d_in[13];
    const float* WO      = (const float*)d_in[14];
    const float* bO      = (const float*)d_in[15];
    const float* ln1s    = (const float*)d_in[16];
    const float* ln1b    = (const float*)d_in[17];
    const float* ln2s    = (const float*)d_in[18];
    const float* ln2b    = (const float*)d_in[19];
    const float* F1      = (const float*)d_in[20];
    const float* c1      = (const float*)d_in[21];
    const float* F2      = (const float*)d_in[22];
    const float* c2      = (const float*)d_in[23];
    const float* Wh      = (const float*)d_in[24];
    const float* bh      = (const float*)d_in[25];
    float* out = (float*)d_out;

    const int M = NB * TOTAL;  // 5120

    char* p = (char*)d_ws;
    float* meanv = (float*)p;    p += 16 * 4;
    float* stdv  = (float*)p;    p += 16 * 4;
    float* acc_head = (float*)p; p += NB * TGT * 4;
    p = (char*)(((size_t)p + 255) & ~255ull);
    float* zn = (float*)p;       p += NB * CTX * 4;
    ushort* u    = (ushort*)p;   p += (size_t)M * DM * 2;
    ushort* qkv  = (ushort*)p;   p += (size_t)3 * M * DM * 2;
    ushort* ax   = (ushort*)p;   p += (size_t)M * DM * 2;
    ushort* o    = (ushort*)p;   p += (size_t)M * DM * 2;
    ushort* hbuf = (ushort*)p;   p += (size_t)M * DFF * 2;
    ushort* zzT  = (ushort*)p;   p += (size_t)M * DM * 2;
    ushort* Wtqkv = (ushort*)p;  p += (size_t)NL * 768 * 256 * 2;
    ushort* WtO   = (ushort*)p;  p += (size_t)NL * 256 * 256 * 2;
    ushort* Ft1   = (ushort*)p;  p += (size_t)NL * 1024 * 256 * 2;
    ushort* Ft2   = (ushort*)p;  p += (size_t)NL * 256 * 1024 * 2;
    p = (char*)(((size_t)p + 255) & ~255ull);
    uint4* sp = (uint4*)p;       p += (size_t)NB * NH * 5 * 10 * 256 * 16;  // 52.4 MB packed bf16 s

    // one-time weight convert+transpose (runs every call; cheap)
    k_convt<<<dim3(8, 8, 4), dim3(32, 32), 0, stream>>>(WQ, Wtqkv + 0,         256, 256, 65536, 768 * 256);
    k_convt<<<dim3(8, 8, 4), dim3(32, 32), 0, stream>>>(WK, Wtqkv + 256 * 256, 256, 256, 65536, 768 * 256);
    k_convt<<<dim3(8, 8, 4), dim3(32, 32), 0, stream>>>(WV, Wtqkv + 512 * 256, 256, 256, 65536, 768 * 256);
    k_convt<<<dim3(8, 8, 4), dim3(32, 32), 0, stream>>>(WO, WtO, 256, 256, 65536, 65536);
    k_convt<<<dim3(32, 8, 4), dim3(32, 32), 0, stream>>>(F1, Ft1, 256, 1024, 262144, 262144);
    k_convt<<<dim3(8, 32, 4), dim3(32, 32), 0, stream>>>(F2, Ft2, 1024, 256, 262144, 262144);

    k_revin<<<NB, 256, 0, stream>>>(z, revin_w, revin_b, zn, meanv, stdv);
    k_embed<<<NB * TOTAL, 256, 0, stream>>>(zn, Wf, bfv, Wc, bcv, Wpos, u);

    for (int l = 0; l < NL; l++) {
        k_gemm_mfma<0, 1><<<dim3(12, 80), 256, 0, stream>>>(
            u, Wtqkv + (size_t)l * 768 * 256, bQ + l * DM, bK + l * DM, bV + l * DM, qkv, M, 768, 256);
        k_attn<<<dim3(NB * NH, 5), 256, 0, stream>>>(qkv, qkv + M * DM, qkv + 2 * M * DM, sp, ax, l > 0 ? 1 : 0);
        k_gemm_mfma<0, 0><<<dim3(4, 80), 256, 0, stream>>>(
            ax, WtO + (size_t)l * 65536, bO + l * DM, bO + l * DM, bO + l * DM, o, M, 256, 256);
        k_add_ln<<<M, 256, 0, stream>>>(u, o, ln1s + l * DM, ln1b + l * DM);
        k_gemm_mfma<1, 0><<<dim3(16, 80), 256, 0, stream>>>(
            u, Ft1 + (size_t)l * 262144, c1 + l * DFF, c1, c1, hbuf, M, 1024, 256);
        k_gemm_mfma<0, 0><<<dim3(4, 80), 256, 0, stream>>>(
            hbuf, Ft2 + (size_t)l * 262144, c2 + l * DM, c2, c2, o, M, 256, 1024);
        k_add_ln<<<M, 256, 0, stream>>>(u, o, ln2s + l * DM, ln2b + l * DM);
    }

    k_transpose<<<dim3(NB, TOTAL / 32, DM / 32), dim3(32, 32), 0, stream>>>(u, zzT);
    hipMemsetAsync(acc_head, 0, NB * TGT * sizeof(float), stream);
    k_head<<<dim3(TGT / 16, 80), 256, 0, stream>>>(zzT, Wh, acc_head);
    k_final<<<(NB * TGT + 255) / 256, 256, 0, stream>>>(acc_head, bh, revin_w, revin_b, meanv, stdv, out);
}

// Round 6
// 541.502 us; speedup vs baseline: 3.9418x; 1.1981x over previous
//
#include <hip/hip_runtime.h>
#include <math.h>

typedef unsigned short ushort;
typedef unsigned int uint;
typedef __attribute__((ext_vector_type(8))) short short8;
typedef __attribute__((ext_vector_type(4))) float f32x4;
typedef __attribute__((ext_vector_type(4))) ushort us4;

constexpr int BS = 2, C_IN = 8, CTX = 1024, TGT = 96;
constexpr int DM = 256, NH = 16, DFF = 1024, NL = 4;
constexpr int NF = 256, TOTAL = 320;
constexpr int NB = 16;
constexpr int DK = 16;
constexpr float EPS = 1e-5f;
constexpr float SCALE = 0.25f;

__device__ __forceinline__ ushort f2b(float x) {
    uint u = __float_as_uint(x);
    u += 0x7fff + ((u >> 16) & 1);
    return (ushort)(u >> 16);
}
__device__ __forceinline__ float bu2f(ushort x) { return __uint_as_float(((uint)x) << 16); }
__device__ __forceinline__ float lo2f(uint p) { return __uint_as_float(p << 16); }
__device__ __forceinline__ float hi2f(uint p) { return __uint_as_float(p & 0xffff0000u); }
__device__ __forceinline__ uint pack2(float a, float b) { return (uint)f2b(a) | ((uint)f2b(b) << 16); }

// ---------------- weight convert + transpose: src fp32 (R x C) -> dst bf16 (C x R) ----------------
__global__ void k_convt(const float* __restrict__ src, ushort* __restrict__ dst,
                        int R, int C, int sls, int dls) {
    __shared__ ushort tile[32][33];
    src += (size_t)blockIdx.z * sls;
    dst += (size_t)blockIdx.z * dls;
    int c0 = blockIdx.x * 32, r0 = blockIdx.y * 32;
    int tx = threadIdx.x, ty = threadIdx.y;
    tile[ty][tx] = f2b(src[(r0 + ty) * C + c0 + tx]);
    __syncthreads();
    dst[(c0 + ty) * R + r0 + tx] = tile[tx][ty];
}

// ---------------- RevIN ----------------
__global__ void k_revin(const float* __restrict__ z, const float* __restrict__ rw,
                        const float* __restrict__ rb, float* __restrict__ zn,
                        float* __restrict__ meanv, float* __restrict__ stdv) {
    int bc = blockIdx.x, t = threadIdx.x;
    __shared__ float r1[256], r2[256];
    float s1 = 0.f, s2 = 0.f;
    for (int i = t; i < CTX; i += 256) {
        float x = z[bc * CTX + i];
        s1 += x; s2 += x * x;
    }
    r1[t] = s1; r2[t] = s2; __syncthreads();
    for (int off = 128; off > 0; off >>= 1) {
        if (t < off) { r1[t] += r1[t + off]; r2[t] += r2[t + off]; }
        __syncthreads();
    }
    float m = r1[0] * (1.0f / CTX);
    float var = r2[0] * (1.0f / CTX) - m * m;
    float sd = sqrtf(var + EPS);
    float w = rw[bc % C_IN], b = rb[bc % C_IN];
    float inv = 1.0f / sd;
    for (int i = t; i < CTX; i += 256) {
        float x = z[bc * CTX + i];
        zn[bc * CTX + i] = (x - m) * inv * w + b;
    }
    if (t == 0) { meanv[bc] = m; stdv[bc] = sd; }
}

// ---------------- dual-scale patch embed + positional -> bf16 u ----------------
__global__ void k_embed(const float* __restrict__ zn, const float* __restrict__ Wf,
                        const float* __restrict__ bfv, const float* __restrict__ Wc,
                        const float* __restrict__ bcv, const float* __restrict__ Wpos,
                        ushort* __restrict__ u) {
    int bc = blockIdx.x / TOTAL, p = blockIdx.x % TOTAL, d = threadIdx.x;
    float acc;
    if (p < NF) {
        acc = bfv[d];
        int base = p * 4;
        for (int i = 0; i < 8; i++) {
            int idx = min(base + i, CTX - 1);
            acc += zn[bc * CTX + idx] * Wf[i * DM + d];
        }
    } else {
        int pc = p - NF;
        acc = bcv[d];
        int base = pc * 16;
        for (int i = 0; i < 32; i++) {
            int idx = min(base + i, CTX - 1);
            acc += zn[bc * CTX + idx] * Wc[i * DM + d];
        }
    }
    acc += Wpos[p * DM + d];
    u[(bc * TOTAL + p) * DM + d] = f2b(acc);
}

// ---------------- bf16 MFMA GEMM: C = A(MxK) @ Wt^T + bias; Wt is (N x K) bf16 ----------------
template <int GELU, int QKV>
__global__ __launch_bounds__(256) void k_gemm_mfma(const ushort* __restrict__ A,
                                                   const ushort* __restrict__ Wt,
                                                   const float* __restrict__ b0,
                                                   const float* __restrict__ b1,
                                                   const float* __restrict__ b2,
                                                   ushort* __restrict__ C,
                                                   int M, int N, int K) {
    __shared__ ushort As[64][40];
    __shared__ ushort Bs[64][40];
    int tid = threadIdx.x;
    int wave = tid >> 6, lane = tid & 63;
    int quad = lane >> 4, l16 = lane & 15;
    int m0 = blockIdx.y * 64, n0 = blockIdx.x * 64;

    f32x4 acc[4];
#pragma unroll
    for (int nt = 0; nt < 4; nt++) acc[nt] = (f32x4){0.f, 0.f, 0.f, 0.f};

    int row = tid >> 2, kc = (tid & 3) * 8;
    for (int k0 = 0; k0 < K; k0 += 32) {
        *(short8*)&As[row][kc] = *(const short8*)&A[(m0 + row) * K + k0 + kc];
        *(short8*)&Bs[row][kc] = *(const short8*)&Wt[(n0 + row) * K + k0 + kc];
        __syncthreads();
        short8 af = *(const short8*)&As[wave * 16 + l16][quad * 8];
#pragma unroll
        for (int nt = 0; nt < 4; nt++) {
            short8 bf = *(const short8*)&Bs[nt * 16 + l16][quad * 8];
            acc[nt] = __builtin_amdgcn_mfma_f32_16x16x32_bf16(af, bf, acc[nt], 0, 0, 0);
        }
        __syncthreads();
    }
#pragma unroll
    for (int nt = 0; nt < 4; nt++) {
        int col = n0 + nt * 16 + l16;
        float bi;
        if (QKV) {
            int bs = (n0 + nt * 16) >> 8;
            const float* bp = bs == 0 ? b0 : (bs == 1 ? b1 : b2);
            bi = bp[col & 255];
        } else {
            bi = b0[col];
        }
#pragma unroll
        for (int r = 0; r < 4; r++) {
            int rowm = m0 + wave * 16 + quad * 4 + r;
            float vv = acc[nt][r] + bi;
            if (GELU) vv = vv * 0.5f * (1.0f + erff(vv * 0.70710678118f));
            if (QKV) C[(col >> 8) * (M * DM) + rowm * DM + (col & 255)] = f2b(vv);
            else C[rowm * N + col] = f2b(vv);
        }
    }
}

// ---------------- MFMA fused attention v3: S^T formulation, no P LDS round-trip ----------------
// grid (NB*NH, 5), block 256 (4 waves x 16 q-rows).
// LDS (30720 B): K frags [0,10240) ushorts: slot ((jt*4+q)*16+(j&15))*8+jj (q>=2 zero);
//                Vt frags [10240,15360): slot ((jt2*4+q)*16+d)*8+jj with permuted j-map:
//                j = jt2*32 + (jj<4 ? q*4+jj : 16+q*4+jj-4)   (matches P-frag k-slot order)
// s chunk: sp[((bh*5+iblk)*10+c)*256 + t], c=0..9; per-lane register-native (S^T) layout.
// mode: 0 = store only (layer 0), 1 = load+add+store, 2 = load+add, no store (last layer)
__global__ __launch_bounds__(256, 4) void k_attn(const ushort* __restrict__ qm, const ushort* __restrict__ km,
                                                 const ushort* __restrict__ vm, uint4* __restrict__ sp,
                                                 ushort* __restrict__ ao, int mode) {
    __shared__ ushort sh[15360];
    uint* sh32 = (uint*)sh;
    int bh = blockIdx.x, b = bh >> 4, h = bh & 15;
    int i0 = blockIdx.y * 64;
    int t = threadIdx.x, wave = t >> 6, lane = t & 63, quad = lane >> 4, l16 = lane & 15;
    const short8 zero8 = (short8){0, 0, 0, 0, 0, 0, 0, 0};

    // stage K frags (A-operand: lane l16 = j&15, quad = dk-half; quads 2,3 zero)
    for (int idx = t; idx < 640; idx += 256) {
        int j = idx >> 1, half = idx & 1;
        short8 kv = *(const short8*)&km[(b * TOTAL + j) * DM + h * DK + half * 8];
        int jt = j >> 4, jl = j & 15;
        *(short8*)&sh[((jt * 4 + half) * 16 + jl) * 8] = kv;
        *(short8*)&sh[((jt * 4 + 2 + half) * 16 + jl) * 8] = zero8;
    }
    // stage Vt frags (permuted j-map)
    for (int idx = t; idx < 320; idx += 256) {
        int jp = idx >> 1, dh = idx & 1;
        int j = jp * 2;
        uint4 a = *(const uint4*)&vm[(b * TOTAL + j) * DM + h * DK + dh * 8];
        uint4 bb = *(const uint4*)&vm[(b * TOTAL + j + 1) * DM + h * DK + dh * 8];
        const ushort* ap = (const ushort*)&a;
        const ushort* bp = (const ushort*)&bb;
        int jr = j & 31;
        int q = (jr & 15) >> 2, jj = ((jr >> 4) << 2) + (jr & 3);  // jj even
        int base = 10240 + ((j >> 5) * 4 + q) * 128 + jj;
#pragma unroll
        for (int dd = 0; dd < 8; dd++) {
            int d = dh * 8 + dd;
            uint val = (uint)ap[dd] | ((uint)bp[dd] << 16);
            sh32[(base + d * 8) >> 1] = val;
        }
    }
    // Q frag (B-operand: lane l16 = q-row m, quad = dk-half; quads 2,3 zero)
    short8 qf = zero8;
    if (quad < 2) qf = *(const short8*)&qm[(b * TOTAL + i0 + wave * 16 + l16) * DM + h * DK + quad * 8];
    __syncthreads();

    // S^T = K Q^T: lane (q,m) gets S[m][j], j = nt*16 + q*4 + r, m = l16
    f32x4 acc[20];
#pragma unroll
    for (int nt = 0; nt < 20; nt++) {
        short8 kf = *(const short8*)&sh[((nt * 4 + quad) * 16 + l16) * 8];
        acc[nt] = __builtin_amdgcn_mfma_f32_16x16x32_bf16(kf, qf, (f32x4){0.f, 0.f, 0.f, 0.f}, 0, 0, 0);
    }

    // scale + prev add + s writeback (coalesced uint4, bf16-packed)
    int cb = (bh * 5 + (int)blockIdx.y) * 10 * 256 + t;
#pragma unroll
    for (int c = 0; c < 10; c++) {
        float e[8];
#pragma unroll
        for (int j = 0; j < 8; j++) e[j] = acc[2 * c + (j >> 2)][j & 3] * SCALE;
        if (mode) {
            uint4 pv = sp[cb + c * 256];
            e[0] += lo2f(pv.x); e[1] += hi2f(pv.x); e[2] += lo2f(pv.y); e[3] += hi2f(pv.y);
            e[4] += lo2f(pv.z); e[5] += hi2f(pv.z); e[6] += lo2f(pv.w); e[7] += hi2f(pv.w);
        }
        if (mode != 2) {
            uint4 ov;
            ov.x = pack2(e[0], e[1]); ov.y = pack2(e[2], e[3]);
            ov.z = pack2(e[4], e[5]); ov.w = pack2(e[6], e[7]);
            sp[cb + c * 256] = ov;
        }
#pragma unroll
        for (int j = 0; j < 8; j++) acc[2 * c + (j >> 2)][j & 3] = e[j];
    }

    // softmax over j: 80 in-lane + cross-quad (lanes ^16, ^32)
    float mx = -1e30f;
#pragma unroll
    for (int nt = 0; nt < 20; nt++)
#pragma unroll
        for (int r = 0; r < 4; r++) mx = fmaxf(mx, acc[nt][r]);
    mx = fmaxf(mx, __shfl_xor(mx, 16));
    mx = fmaxf(mx, __shfl_xor(mx, 32));
    float sum = 0.f;
#pragma unroll
    for (int nt = 0; nt < 20; nt++)
#pragma unroll
        for (int r = 0; r < 4; r++) { acc[nt][r] = __expf(acc[nt][r] - mx); sum += acc[nt][r]; }
    sum += __shfl_xor(sum, 16);
    sum += __shfl_xor(sum, 32);
    float inv = 1.f / sum;
#pragma unroll
    for (int nt = 0; nt < 20; nt++)
#pragma unroll
        for (int r = 0; r < 4; r++) acc[nt][r] *= inv;

    // PV: o^T = V^T P^T. A = Vt frags (lane l16 = d), B = P^T = own registers (k-permuted).
    f32x4 oacc = (f32x4){0.f, 0.f, 0.f, 0.f};
#pragma unroll
    for (int jt2 = 0; jt2 < 10; jt2++) {
        short8 vt = *(const short8*)&sh[10240 + ((jt2 * 4 + quad) * 16 + l16) * 8];
        union { short8 v; uint u[4]; } pf;
        pf.u[0] = pack2(acc[2 * jt2][0], acc[2 * jt2][1]);
        pf.u[1] = pack2(acc[2 * jt2][2], acc[2 * jt2][3]);
        pf.u[2] = pack2(acc[2 * jt2 + 1][0], acc[2 * jt2 + 1][1]);
        pf.u[3] = pack2(acc[2 * jt2 + 1][2], acc[2 * jt2 + 1][3]);
        oacc = __builtin_amdgcn_mfma_f32_16x16x32_bf16(vt, pf.v, oacc, 0, 0, 0);
    }
    // lane (q, m=l16) holds o[m][d = q*4+r] -> one 8B store
    us4 ov4 = (us4){f2b(oacc[0]), f2b(oacc[1]), f2b(oacc[2]), f2b(oacc[3])};
    *(us4*)&ao[(b * TOTAL + i0 + wave * 16 + l16) * DM + h * DK + quad * 4] = ov4;
}

// ---------------- residual add + LayerNorm (bf16 in/out, fp32 math) ----------------
__global__ void k_add_ln(ushort* __restrict__ u, const ushort* __restrict__ o,
                         const float* __restrict__ ls, const float* __restrict__ lb) {
    int row = blockIdx.x, d = threadIdx.x;
    __shared__ float r1[256], r2[256];
    float x = bu2f(u[row * DM + d]) + bu2f(o[row * DM + d]);
    r1[d] = x; r2[d] = x * x; __syncthreads();
    for (int off = 128; off > 0; off >>= 1) {
        if (d < off) { r1[d] += r1[d + off]; r2[d] += r2[d + off]; }
        __syncthreads();
    }
    float m = r1[0] * (1.0f / DM);
    float var = r2[0] * (1.0f / DM) - m * m;
    float rs = rsqrtf(var + EPS);
    u[row * DM + d] = f2b((x - m) * rs * ls[d] + lb[d]);
}

// ---------------- transpose u (bc,p,d) -> zzT (bc, d*TOTAL+p), bf16 ----------------
__global__ void k_transpose(const ushort* __restrict__ u, ushort* __restrict__ zzT) {
    __shared__ ushort tile[32][34];
    int bc = blockIdx.x, p0 = blockIdx.y * 32, d0 = blockIdx.z * 32;
    int tx = threadIdx.x, ty = threadIdx.y;
    tile[ty][tx] = u[(bc * TOTAL + p0 + ty) * DM + d0 + tx];
    __syncthreads();
    zzT[bc * (DM * TOTAL) + (d0 + ty) * TOTAL + p0 + tx] = tile[tx][ty];
}

// ---------------- head GEMM: acc += zzT(16x81920 bf16) @ Wh(81920x96 fp32) ----------------
__global__ void k_head(const ushort* __restrict__ zzT, const float* __restrict__ Wh,
                       float* __restrict__ acc_head) {
    int t0 = blockIdx.x * 16;
    int k0 = blockIdx.y * 1024;
    int tx = threadIdx.x & 15, ty = threadIdx.x >> 4;
    __shared__ float whs[16][17];
    __shared__ float zs[16][17];
    float acc = 0.f;
    for (int kb = 0; kb < 1024; kb += 16) {
        whs[ty][tx] = Wh[(k0 + kb + ty) * TGT + t0 + tx];
        zs[ty][tx] = bu2f(zzT[ty * (DM * TOTAL) + k0 + kb + tx]);
        __syncthreads();
        for (int kk = 0; kk < 16; kk++) acc += zs[ty][kk] * whs[kk][tx];
        __syncthreads();
    }
    atomicAdd(&acc_head[ty * TGT + t0 + tx], acc);
}

// ---------------- final ----------------
__global__ void k_final(const float* __restrict__ acc_head, const float* __restrict__ bh,
                        const float* __restrict__ rw, const float* __restrict__ rb,
                        const float* __restrict__ meanv, const float* __restrict__ stdv,
                        float* __restrict__ out) {
    int idx = blockIdx.x * 256 + threadIdx.x;
    if (idx >= NB * TGT) return;
    int bc = idx / TGT, t = idx % TGT, c = bc % C_IN;
    float vv = acc_head[idx] + bh[t];
    vv = (vv - rb[c]) / (rw[c] + EPS * EPS) * stdv[bc] + meanv[bc];
    out[idx] = vv;
}

extern "C" void kernel_launch(void* const* d_in, const int* in_sizes, int n_in,
                              void* d_out, int out_size, void* d_ws, size_t ws_size,
                              hipStream_t stream) {
    const float* z       = (const float*)d_in[0];
    const float* revin_w = (const float*)d_in[1];
    const float* revin_b = (const float*)d_in[2];
    const float* Wf      = (const float*)d_in[3];
    const float* bfv     = (const float*)d_in[4];
    const float* Wc      = (const float*)d_in[5];
    const float* bcv     = (const float*)d_in[6];
    const float* Wpos    = (const float*)d_in[7];
    const float* WQ      = (const float*)d_in[8];
    const float* bQ      = (const float*)d_in[9];
    const float* WK      = (const float*)d_in[10];
    const float* bK      = (const float*)d_in[11];
    const float* WV      = (const float*)d_in[12];
    const float* bV      = (const float*)d_in[13];
    const float* WO      = (const float*)d_in[14];
    const float* bO      = (const float*)d_in[15];
    const float* ln1s    = (const float*)d_in[16];
    const float* ln1b    = (const float*)d_in[17];
    const float* ln2s    = (const float*)d_in[18];
    const float* ln2b    = (const float*)d_in[19];
    const float* F1      = (const float*)d_in[20];
    const float* c1      = (const float*)d_in[21];
    const float* F2      = (const float*)d_in[22];
    const float* c2      = (const float*)d_in[23];
    const float* Wh      = (const float*)d_in[24];
    const float* bh      = (const float*)d_in[25];
    float* out = (float*)d_out;

    const int M = NB * TOTAL;  // 5120

    char* p = (char*)d_ws;
    float* meanv = (float*)p;    p += 16 * 4;
    float* stdv  = (float*)p;    p += 16 * 4;
    float* acc_head = (float*)p; p += NB * TGT * 4;
    p = (char*)(((size_t)p + 255) & ~255ull);
    float* zn = (float*)p;       p += NB * CTX * 4;
    ushort* u    = (ushort*)p;   p += (size_t)M * DM * 2;
    ushort* qkv  = (ushort*)p;   p += (size_t)3 * M * DM * 2;
    ushort* ax   = (ushort*)p;   p += (size_t)M * DM * 2;
    ushort* o    = (ushort*)p;   p += (size_t)M * DM * 2;
    ushort* hbuf = (ushort*)p;   p += (size_t)M * DFF * 2;
    ushort* zzT  = (ushort*)p;   p += (size_t)M * DM * 2;
    ushort* Wtqkv = (ushort*)p;  p += (size_t)NL * 768 * 256 * 2;
    ushort* WtO   = (ushort*)p;  p += (size_t)NL * 256 * 256 * 2;
    ushort* Ft1   = (ushort*)p;  p += (size_t)NL * 1024 * 256 * 2;
    ushort* Ft2   = (ushort*)p;  p += (size_t)NL * 256 * 1024 * 2;
    p = (char*)(((size_t)p + 255) & ~255ull);
    uint4* sp = (uint4*)p;       p += (size_t)NB * NH * 5 * 10 * 256 * 16;  // 52.4 MB packed bf16 s

    k_convt<<<dim3(8, 8, 4), dim3(32, 32), 0, stream>>>(WQ, Wtqkv + 0,         256, 256, 65536, 768 * 256);
    k_convt<<<dim3(8, 8, 4), dim3(32, 32), 0, stream>>>(WK, Wtqkv + 256 * 256, 256, 256, 65536, 768 * 256);
    k_convt<<<dim3(8, 8, 4), dim3(32, 32), 0, stream>>>(WV, Wtqkv + 512 * 256, 256, 256, 65536, 768 * 256);
    k_convt<<<dim3(8, 8, 4), dim3(32, 32), 0, stream>>>(WO, WtO, 256, 256, 65536, 65536);
    k_convt<<<dim3(32, 8, 4), dim3(32, 32), 0, stream>>>(F1, Ft1, 256, 1024, 262144, 262144);
    k_convt<<<dim3(8, 32, 4), dim3(32, 32), 0, stream>>>(F2, Ft2, 1024, 256, 262144, 262144);

    k_revin<<<NB, 256, 0, stream>>>(z, revin_w, revin_b, zn, meanv, stdv);
    k_embed<<<NB * TOTAL, 256, 0, stream>>>(zn, Wf, bfv, Wc, bcv, Wpos, u);

    for (int l = 0; l < NL; l++) {
        int mode = (l == 0) ? 0 : (l == NL - 1 ? 2 : 1);
        k_gemm_mfma<0, 1><<<dim3(12, 80), 256, 0, stream>>>(
            u, Wtqkv + (size_t)l * 768 * 256, bQ + l * DM, bK + l * DM, bV + l * DM, qkv, M, 768, 256);
        k_attn<<<dim3(NB * NH, 5), 256, 0, stream>>>(qkv, qkv + M * DM, qkv + 2 * M * DM, sp, ax, mode);
        k_gemm_mfma<0, 0><<<dim3(4, 80), 256, 0, stream>>>(
            ax, WtO + (size_t)l * 65536, bO + l * DM, bO + l * DM, bO + l * DM, o, M, 256, 256);
        k_add_ln<<<M, 256, 0, stream>>>(u, o, ln1s + l * DM, ln1b + l * DM);
        k_gemm_mfma<1, 0><<<dim3(16, 80), 256, 0, stream>>>(
            u, Ft1 + (size_t)l * 262144, c1 + l * DFF, c1, c1, hbuf, M, 1024, 256);
        k_gemm_mfma<0, 0><<<dim3(4, 80), 256, 0, stream>>>(
            hbuf, Ft2 + (size_t)l * 262144, c2 + l * DM, c2, c2, o, M, 256, 1024);
        k_add_ln<<<M, 256, 0, stream>>>(u, o, ln2s + l * DM, ln2b + l * DM);
    }

    k_transpose<<<dim3(NB, TOTAL / 32, DM / 32), dim3(32, 32), 0, stream>>>(u, zzT);
    hipMemsetAsync(acc_head, 0, NB * TGT * sizeof(float), stream);
    k_head<<<dim3(TGT / 16, 80), 256, 0, stream>>>(zzT, Wh, acc_head);
    k_final<<<(NB * TGT + 255) / 256, 256, 0, stream>>>(acc_head, bh, revin_w, revin_b, meanv, stdv, out);
}

// Round 7
// 517.038 us; speedup vs baseline: 4.1283x; 1.0473x over previous
//
#include <hip/hip_runtime.h>
#include <math.h>

typedef unsigned short ushort;
typedef unsigned int uint;
typedef __attribute__((ext_vector_type(8))) short short8;
typedef __attribute__((ext_vector_type(4))) float f32x4;
typedef __attribute__((ext_vector_type(4))) ushort us4;

constexpr int BS = 2, C_IN = 8, CTX = 1024, TGT = 96;
constexpr int DM = 256, NH = 16, DFF = 1024, NL = 4;
constexpr int NF = 256, TOTAL = 320;
constexpr int NB = 16;
constexpr int DK = 16;
constexpr float EPS = 1e-5f;
constexpr float SCALE = 0.25f;
constexpr int KHEAD = DM * TOTAL;  // 81920

__device__ __forceinline__ ushort f2b(float x) {
    uint u = __float_as_uint(x);
    u += 0x7fff + ((u >> 16) & 1);
    return (ushort)(u >> 16);
}
__device__ __forceinline__ float bu2f(ushort x) { return __uint_as_float(((uint)x) << 16); }
__device__ __forceinline__ float lo2f(uint p) { return __uint_as_float(p << 16); }
__device__ __forceinline__ float hi2f(uint p) { return __uint_as_float(p & 0xffff0000u); }
__device__ __forceinline__ uint pack2(float a, float b) { return (uint)f2b(a) | ((uint)f2b(b) << 16); }

// ---------------- weight convert + transpose: src fp32 (R x C) -> dst bf16 (C x R) ----------------
__global__ void k_convt(const float* __restrict__ src, ushort* __restrict__ dst,
                        int R, int C, int sls, int dls) {
    __shared__ ushort tile[32][33];
    src += (size_t)blockIdx.z * sls;
    dst += (size_t)blockIdx.z * dls;
    int c0 = blockIdx.x * 32, r0 = blockIdx.y * 32;
    int tx = threadIdx.x, ty = threadIdx.y;
    tile[ty][tx] = f2b(src[(r0 + ty) * C + c0 + tx]);
    __syncthreads();
    dst[(c0 + ty) * R + r0 + tx] = tile[tx][ty];
}

// ---------------- RevIN ----------------
__global__ void k_revin(const float* __restrict__ z, const float* __restrict__ rw,
                        const float* __restrict__ rb, float* __restrict__ zn,
                        float* __restrict__ meanv, float* __restrict__ stdv) {
    int bc = blockIdx.x, t = threadIdx.x;
    __shared__ float r1[256], r2[256];
    float s1 = 0.f, s2 = 0.f;
    for (int i = t; i < CTX; i += 256) {
        float x = z[bc * CTX + i];
        s1 += x; s2 += x * x;
    }
    r1[t] = s1; r2[t] = s2; __syncthreads();
    for (int off = 128; off > 0; off >>= 1) {
        if (t < off) { r1[t] += r1[t + off]; r2[t] += r2[t + off]; }
        __syncthreads();
    }
    float m = r1[0] * (1.0f / CTX);
    float var = r2[0] * (1.0f / CTX) - m * m;
    float sd = sqrtf(var + EPS);
    float w = rw[bc % C_IN], b = rb[bc % C_IN];
    float inv = 1.0f / sd;
    for (int i = t; i < CTX; i += 256) {
        float x = z[bc * CTX + i];
        zn[bc * CTX + i] = (x - m) * inv * w + b;
    }
    if (t == 0) { meanv[bc] = m; stdv[bc] = sd; }
}

// ---------------- dual-scale patch embed + positional -> bf16 u ----------------
__global__ void k_embed(const float* __restrict__ zn, const float* __restrict__ Wf,
                        const float* __restrict__ bfv, const float* __restrict__ Wc,
                        const float* __restrict__ bcv, const float* __restrict__ Wpos,
                        ushort* __restrict__ u) {
    int bc = blockIdx.x / TOTAL, p = blockIdx.x % TOTAL, d = threadIdx.x;
    float acc;
    if (p < NF) {
        acc = bfv[d];
        int base = p * 4;
        for (int i = 0; i < 8; i++) {
            int idx = min(base + i, CTX - 1);
            acc += zn[bc * CTX + idx] * Wf[i * DM + d];
        }
    } else {
        int pc = p - NF;
        acc = bcv[d];
        int base = pc * 16;
        for (int i = 0; i < 32; i++) {
            int idx = min(base + i, CTX - 1);
            acc += zn[bc * CTX + idx] * Wc[i * DM + d];
        }
    }
    acc += Wpos[p * DM + d];
    u[(bc * TOTAL + p) * DM + d] = f2b(acc);
}

// ---------------- bf16 MFMA GEMM: C = A(MxK) @ Wt^T + bias; Wt is (N x K) bf16 ----------------
// 128x64 block tile, 4 waves; wave = 32 rows x 64 cols (2 A-frags x 4 B-frags, 8 MFMAs/k-step)
template <int GELU, int QKV>
__global__ __launch_bounds__(256) void k_gemm_mfma(const ushort* __restrict__ A,
                                                   const ushort* __restrict__ Wt,
                                                   const float* __restrict__ b0,
                                                   const float* __restrict__ b1,
                                                   const float* __restrict__ b2,
                                                   ushort* __restrict__ C,
                                                   int M, int N, int K) {
    __shared__ ushort As[128][40];
    __shared__ ushort Bs[64][40];
    int tid = threadIdx.x;
    int wave = tid >> 6, lane = tid & 63;
    int quad = lane >> 4, l16 = lane & 15;
    int m0 = blockIdx.y * 128, n0 = blockIdx.x * 64;

    f32x4 acc[2][4];
#pragma unroll
    for (int g = 0; g < 2; g++)
#pragma unroll
        for (int nt = 0; nt < 4; nt++) acc[g][nt] = (f32x4){0.f, 0.f, 0.f, 0.f};

    int arow = tid >> 2, akc = (tid & 3) * 8;
    for (int k0 = 0; k0 < K; k0 += 32) {
        *(short8*)&As[arow][akc] = *(const short8*)&A[(m0 + arow) * K + k0 + akc];
        *(short8*)&As[64 + arow][akc] = *(const short8*)&A[(m0 + 64 + arow) * K + k0 + akc];
        *(short8*)&Bs[arow][akc] = *(const short8*)&Wt[(n0 + arow) * K + k0 + akc];
        __syncthreads();
        short8 af0 = *(const short8*)&As[wave * 32 + l16][quad * 8];
        short8 af1 = *(const short8*)&As[wave * 32 + 16 + l16][quad * 8];
#pragma unroll
        for (int nt = 0; nt < 4; nt++) {
            short8 bf = *(const short8*)&Bs[nt * 16 + l16][quad * 8];
            acc[0][nt] = __builtin_amdgcn_mfma_f32_16x16x32_bf16(af0, bf, acc[0][nt], 0, 0, 0);
            acc[1][nt] = __builtin_amdgcn_mfma_f32_16x16x32_bf16(af1, bf, acc[1][nt], 0, 0, 0);
        }
        __syncthreads();
    }
#pragma unroll
    for (int nt = 0; nt < 4; nt++) {
        int col = n0 + nt * 16 + l16;
        float bi;
        if (QKV) {
            int bs = (n0 + nt * 16) >> 8;
            const float* bp = bs == 0 ? b0 : (bs == 1 ? b1 : b2);
            bi = bp[col & 255];
        } else {
            bi = b0[col];
        }
#pragma unroll
        for (int g = 0; g < 2; g++)
#pragma unroll
            for (int r = 0; r < 4; r++) {
                int rowm = m0 + wave * 32 + g * 16 + quad * 4 + r;
                float vv = acc[g][nt][r] + bi;
                if (GELU) vv = vv * 0.5f * (1.0f + erff(vv * 0.70710678118f));
                if (QKV) C[(col >> 8) * (M * DM) + rowm * DM + (col & 255)] = f2b(vv);
                else C[rowm * N + col] = f2b(vv);
            }
    }
}

// ---------------- MFMA fused attention v3: S^T formulation (unchanged from R6) ----------------
__global__ __launch_bounds__(256, 4) void k_attn(const ushort* __restrict__ qm, const ushort* __restrict__ km,
                                                 const ushort* __restrict__ vm, uint4* __restrict__ sp,
                                                 ushort* __restrict__ ao, int mode) {
    __shared__ ushort sh[15360];
    uint* sh32 = (uint*)sh;
    int bh = blockIdx.x, b = bh >> 4, h = bh & 15;
    int i0 = blockIdx.y * 64;
    int t = threadIdx.x, wave = t >> 6, lane = t & 63, quad = lane >> 4, l16 = lane & 15;
    const short8 zero8 = (short8){0, 0, 0, 0, 0, 0, 0, 0};

    for (int idx = t; idx < 640; idx += 256) {
        int j = idx >> 1, half = idx & 1;
        short8 kv = *(const short8*)&km[(b * TOTAL + j) * DM + h * DK + half * 8];
        int jt = j >> 4, jl = j & 15;
        *(short8*)&sh[((jt * 4 + half) * 16 + jl) * 8] = kv;
        *(short8*)&sh[((jt * 4 + 2 + half) * 16 + jl) * 8] = zero8;
    }
    for (int idx = t; idx < 320; idx += 256) {
        int jp = idx >> 1, dh = idx & 1;
        int j = jp * 2;
        uint4 a = *(const uint4*)&vm[(b * TOTAL + j) * DM + h * DK + dh * 8];
        uint4 bb = *(const uint4*)&vm[(b * TOTAL + j + 1) * DM + h * DK + dh * 8];
        const ushort* ap = (const ushort*)&a;
        const ushort* bp = (const ushort*)&bb;
        int jr = j & 31;
        int q = (jr & 15) >> 2, jj = ((jr >> 4) << 2) + (jr & 3);
        int base = 10240 + ((j >> 5) * 4 + q) * 128 + jj;
#pragma unroll
        for (int dd = 0; dd < 8; dd++) {
            int d = dh * 8 + dd;
            uint val = (uint)ap[dd] | ((uint)bp[dd] << 16);
            sh32[(base + d * 8) >> 1] = val;
        }
    }
    short8 qf = zero8;
    if (quad < 2) qf = *(const short8*)&qm[(b * TOTAL + i0 + wave * 16 + l16) * DM + h * DK + quad * 8];
    __syncthreads();

    f32x4 acc[20];
#pragma unroll
    for (int nt = 0; nt < 20; nt++) {
        short8 kf = *(const short8*)&sh[((nt * 4 + quad) * 16 + l16) * 8];
        acc[nt] = __builtin_amdgcn_mfma_f32_16x16x32_bf16(kf, qf, (f32x4){0.f, 0.f, 0.f, 0.f}, 0, 0, 0);
    }

    int cb = (bh * 5 + (int)blockIdx.y) * 10 * 256 + t;
#pragma unroll
    for (int c = 0; c < 10; c++) {
        float e[8];
#pragma unroll
        for (int j = 0; j < 8; j++) e[j] = acc[2 * c + (j >> 2)][j & 3] * SCALE;
        if (mode) {
            uint4 pv = sp[cb + c * 256];
            e[0] += lo2f(pv.x); e[1] += hi2f(pv.x); e[2] += lo2f(pv.y); e[3] += hi2f(pv.y);
            e[4] += lo2f(pv.z); e[5] += hi2f(pv.z); e[6] += lo2f(pv.w); e[7] += hi2f(pv.w);
        }
        if (mode != 2) {
            uint4 ov;
            ov.x = pack2(e[0], e[1]); ov.y = pack2(e[2], e[3]);
            ov.z = pack2(e[4], e[5]); ov.w = pack2(e[6], e[7]);
            sp[cb + c * 256] = ov;
        }
#pragma unroll
        for (int j = 0; j < 8; j++) acc[2 * c + (j >> 2)][j & 3] = e[j];
    }

    float mx = -1e30f;
#pragma unroll
    for (int nt = 0; nt < 20; nt++)
#pragma unroll
        for (int r = 0; r < 4; r++) mx = fmaxf(mx, acc[nt][r]);
    mx = fmaxf(mx, __shfl_xor(mx, 16));
    mx = fmaxf(mx, __shfl_xor(mx, 32));
    float sum = 0.f;
#pragma unroll
    for (int nt = 0; nt < 20; nt++)
#pragma unroll
        for (int r = 0; r < 4; r++) { acc[nt][r] = __expf(acc[nt][r] - mx); sum += acc[nt][r]; }
    sum += __shfl_xor(sum, 16);
    sum += __shfl_xor(sum, 32);
    float inv = 1.f / sum;
#pragma unroll
    for (int nt = 0; nt < 20; nt++)
#pragma unroll
        for (int r = 0; r < 4; r++) acc[nt][r] *= inv;

    f32x4 oacc = (f32x4){0.f, 0.f, 0.f, 0.f};
#pragma unroll
    for (int jt2 = 0; jt2 < 10; jt2++) {
        short8 vt = *(const short8*)&sh[10240 + ((jt2 * 4 + quad) * 16 + l16) * 8];
        union { short8 v; uint u[4]; } pf;
        pf.u[0] = pack2(acc[2 * jt2][0], acc[2 * jt2][1]);
        pf.u[1] = pack2(acc[2 * jt2][2], acc[2 * jt2][3]);
        pf.u[2] = pack2(acc[2 * jt2 + 1][0], acc[2 * jt2 + 1][1]);
        pf.u[3] = pack2(acc[2 * jt2 + 1][2], acc[2 * jt2 + 1][3]);
        oacc = __builtin_amdgcn_mfma_f32_16x16x32_bf16(vt, pf.v, oacc, 0, 0, 0);
    }
    us4 ov4 = (us4){f2b(oacc[0]), f2b(oacc[1]), f2b(oacc[2]), f2b(oacc[3])};
    *(us4*)&ao[(b * TOTAL + i0 + wave * 16 + l16) * DM + h * DK + quad * 4] = ov4;
}

// ---------------- residual add + LayerNorm: wave per row, no LDS/barriers ----------------
__global__ __launch_bounds__(256) void k_add_ln(ushort* __restrict__ u, const ushort* __restrict__ o,
                                                const float* __restrict__ ls, const float* __restrict__ lb) {
    int wave = threadIdx.x >> 6, lane = threadIdx.x & 63;
    int row = blockIdx.x * 4 + wave;
    int d0 = lane * 4;
    uint2 uv = *(const uint2*)&u[row * DM + d0];
    uint2 ov = *(const uint2*)&o[row * DM + d0];
    float x0 = lo2f(uv.x) + lo2f(ov.x);
    float x1 = hi2f(uv.x) + hi2f(ov.x);
    float x2 = lo2f(uv.y) + lo2f(ov.y);
    float x3 = hi2f(uv.y) + hi2f(ov.y);
    float sum = x0 + x1 + x2 + x3;
    float sq = x0 * x0 + x1 * x1 + x2 * x2 + x3 * x3;
#pragma unroll
    for (int off = 1; off < 64; off <<= 1) {
        sum += __shfl_xor(sum, off);
        sq += __shfl_xor(sq, off);
    }
    float m = sum * (1.0f / DM);
    float var = sq * (1.0f / DM) - m * m;
    float rs = rsqrtf(var + EPS);
    f32x4 sc = *(const f32x4*)&ls[d0];
    f32x4 bb = *(const f32x4*)&lb[d0];
    float y0 = (x0 - m) * rs * sc[0] + bb[0];
    float y1 = (x1 - m) * rs * sc[1] + bb[1];
    float y2 = (x2 - m) * rs * sc[2] + bb[2];
    float y3 = (x3 - m) * rs * sc[3] + bb[3];
    uint2 w;
    w.x = pack2(y0, y1); w.y = pack2(y2, y3);
    *(uint2*)&u[row * DM + d0] = w;
}

// ---------------- transpose u (bc,p,d) -> zzT (bc, d*TOTAL+p), bf16 ----------------
__global__ void k_transpose(const ushort* __restrict__ u, ushort* __restrict__ zzT) {
    __shared__ ushort tile[32][34];
    int bc = blockIdx.x, p0 = blockIdx.y * 32, d0 = blockIdx.z * 32;
    int tx = threadIdx.x, ty = threadIdx.y;
    tile[ty][tx] = u[(bc * TOTAL + p0 + ty) * DM + d0 + tx];
    __syncthreads();
    zzT[bc * (DM * TOTAL) + (d0 + ty) * TOTAL + p0 + tx] = tile[tx][ty];
}

// ---------------- head GEMM: MFMA split-K, frags straight from global ----------------
// grid (6, 20), block 256; wave handles K-chunk of 1024 (32 MFMAs), atomicAdd epilogue.
__global__ __launch_bounds__(256) void k_head(const ushort* __restrict__ zzT, const ushort* __restrict__ WhT,
                                              float* __restrict__ acc_head) {
    int t0 = blockIdx.x * 16;
    int wave = threadIdx.x >> 6, lane = threadIdx.x & 63;
    int quad = lane >> 4, l16 = lane & 15;
    int kbeg = (blockIdx.y * 4 + wave) * 1024;
    f32x4 acc = (f32x4){0.f, 0.f, 0.f, 0.f};
    const ushort* za = &zzT[l16 * KHEAD + quad * 8];
    const ushort* wb = &WhT[(t0 + l16) * KHEAD + quad * 8];
#pragma unroll 4
    for (int k = kbeg; k < kbeg + 1024; k += 32) {
        short8 af = *(const short8*)&za[k];
        short8 bf = *(const short8*)&wb[k];
        acc = __builtin_amdgcn_mfma_f32_16x16x32_bf16(af, bf, acc, 0, 0, 0);
    }
#pragma unroll
    for (int r = 0; r < 4; r++)
        atomicAdd(&acc_head[(quad * 4 + r) * TGT + t0 + l16], acc[r]);
}

// ---------------- final ----------------
__global__ void k_final(const float* __restrict__ acc_head, const float* __restrict__ bh,
                        const float* __restrict__ rw, const float* __restrict__ rb,
                        const float* __restrict__ meanv, const float* __restrict__ stdv,
                        float* __restrict__ out) {
    int idx = blockIdx.x * 256 + threadIdx.x;
    if (idx >= NB * TGT) return;
    int bc = idx / TGT, t = idx % TGT, c = bc % C_IN;
    float vv = acc_head[idx] + bh[t];
    vv = (vv - rb[c]) / (rw[c] + EPS * EPS) * stdv[bc] + meanv[bc];
    out[idx] = vv;
}

extern "C" void kernel_launch(void* const* d_in, const int* in_sizes, int n_in,
                              void* d_out, int out_size, void* d_ws, size_t ws_size,
                              hipStream_t stream) {
    const float* z       = (const float*)d_in[0];
    const float* revin_w = (const float*)d_in[1];
    const float* revin_b = (const float*)d_in[2];
    const float* Wf      = (const float*)d_in[3];
    const float* bfv     = (const float*)d_in[4];
    const float* Wc      = (const float*)d_in[5];
    const float* bcv     = (const float*)d_in[6];
    const float* Wpos    = (const float*)d_in[7];
    const float* WQ      = (const float*)d_in[8];
    const float* bQ      = (const float*)d_in[9];
    const float* WK      = (const float*)d_in[10];
    const float* bK      = (const float*)d_in[11];
    const float* WV      = (const float*)d_in[12];
    const float* bV      = (const float*)d_in[13];
    const float* WO      = (const float*)d_in[14];
    const float* bO      = (const float*)d_in[15];
    const float* ln1s    = (const float*)d_in[16];
    const float* ln1b    = (const float*)d_in[17];
    const float* ln2s    = (const float*)d_in[18];
    const float* ln2b    = (const float*)d_in[19];
    const float* F1      = (const float*)d_in[20];
    const float* c1      = (const float*)d_in[21];
    const float* F2      = (const float*)d_in[22];
    const float* c2      = (const float*)d_in[23];
    const float* Wh      = (const float*)d_in[24];
    const float* bh      = (const float*)d_in[25];
    float* out = (float*)d_out;

    const int M = NB * TOTAL;  // 5120

    char* p = (char*)d_ws;
    float* meanv = (float*)p;    p += 16 * 4;
    float* stdv  = (float*)p;    p += 16 * 4;
    float* acc_head = (float*)p; p += NB * TGT * 4;
    p = (char*)(((size_t)p + 255) & ~255ull);
    float* zn = (float*)p;       p += NB * CTX * 4;
    ushort* u    = (ushort*)p;   p += (size_t)M * DM * 2;
    ushort* qkv  = (ushort*)p;   p += (size_t)3 * M * DM * 2;
    ushort* ax   = (ushort*)p;   p += (size_t)M * DM * 2;
    ushort* o    = (ushort*)p;   p += (size_t)M * DM * 2;
    ushort* hbuf = (ushort*)p;   p += (size_t)M * DFF * 2;
    ushort* zzT  = (ushort*)p;   p += (size_t)M * DM * 2;
    ushort* Wtqkv = (ushort*)p;  p += (size_t)NL * 768 * 256 * 2;
    ushort* WtO   = (ushort*)p;  p += (size_t)NL * 256 * 256 * 2;
    ushort* Ft1   = (ushort*)p;  p += (size_t)NL * 1024 * 256 * 2;
    ushort* Ft2   = (ushort*)p;  p += (size_t)NL * 256 * 1024 * 2;
    ushort* WhT   = (ushort*)p;  p += (size_t)TGT * KHEAD * 2;   // 15.7 MB
    p = (char*)(((size_t)p + 255) & ~255ull);
    uint4* sp = (uint4*)p;       p += (size_t)NB * NH * 5 * 10 * 256 * 16;  // 52.4 MB packed bf16 s

    k_convt<<<dim3(8, 8, 4), dim3(32, 32), 0, stream>>>(WQ, Wtqkv + 0,         256, 256, 65536, 768 * 256);
    k_convt<<<dim3(8, 8, 4), dim3(32, 32), 0, stream>>>(WK, Wtqkv + 256 * 256, 256, 256, 65536, 768 * 256);
    k_convt<<<dim3(8, 8, 4), dim3(32, 32), 0, stream>>>(WV, Wtqkv + 512 * 256, 256, 256, 65536, 768 * 256);
    k_convt<<<dim3(8, 8, 4), dim3(32, 32), 0, stream>>>(WO, WtO, 256, 256, 65536, 65536);
    k_convt<<<dim3(32, 8, 4), dim3(32, 32), 0, stream>>>(F1, Ft1, 256, 1024, 262144, 262144);
    k_convt<<<dim3(8, 32, 4), dim3(32, 32), 0, stream>>>(F2, Ft2, 1024, 256, 262144, 262144);
    k_convt<<<dim3(3, 2560, 1), dim3(32, 32), 0, stream>>>(Wh, WhT, KHEAD, TGT, 0, 0);

    k_revin<<<NB, 256, 0, stream>>>(z, revin_w, revin_b, zn, meanv, stdv);
    k_embed<<<NB * TOTAL, 256, 0, stream>>>(zn, Wf, bfv, Wc, bcv, Wpos, u);

    for (int l = 0; l < NL; l++) {
        int mode = (l == 0) ? 0 : (l == NL - 1 ? 2 : 1);
        k_gemm_mfma<0, 1><<<dim3(12, 40), 256, 0, stream>>>(
            u, Wtqkv + (size_t)l * 768 * 256, bQ + l * DM, bK + l * DM, bV + l * DM, qkv, M, 768, 256);
        k_attn<<<dim3(NB * NH, 5), 256, 0, stream>>>(qkv, qkv + M * DM, qkv + 2 * M * DM, sp, ax, mode);
        k_gemm_mfma<0, 0><<<dim3(4, 40), 256, 0, stream>>>(
            ax, WtO + (size_t)l * 65536, bO + l * DM, bO + l * DM, bO + l * DM, o, M, 256, 256);
        k_add_ln<<<M / 4, 256, 0, stream>>>(u, o, ln1s + l * DM, ln1b + l * DM);
        k_gemm_mfma<1, 0><<<dim3(16, 40), 256, 0, stream>>>(
            u, Ft1 + (size_t)l * 262144, c1 + l * DFF, c1, c1, hbuf, M, 1024, 256);
        k_gemm_mfma<0, 0><<<dim3(4, 40), 256, 0, stream>>>(
            hbuf, Ft2 + (size_t)l * 262144, c2 + l * DM, c2, c2, o, M, 256, 1024);
        k_add_ln<<<M / 4, 256, 0, stream>>>(u, o, ln2s + l * DM, ln2b + l * DM);
    }

    k_transpose<<<dim3(NB, TOTAL / 32, DM / 32), dim3(32, 32), 0, stream>>>(u, zzT);
    hipMemsetAsync(acc_head, 0, NB * TGT * sizeof(float), stream);
    k_head<<<dim3(TGT / 16, 20), 256, 0, stream>>>(zzT, WhT, acc_head);
    k_final<<<(NB * TGT + 255) / 256, 256, 0, stream>>>(acc_head, bh, revin_w, revin_b, meanv, stdv, out);
}

// Round 8
// 500.292 us; speedup vs baseline: 4.2665x; 1.0335x over previous
//
#include <hip/hip_runtime.h>
#include <math.h>

typedef unsigned short ushort;
typedef unsigned int uint;
typedef __attribute__((ext_vector_type(8))) short short8;
typedef __attribute__((ext_vector_type(4))) float f32x4;
typedef __attribute__((ext_vector_type(4))) ushort us4;

constexpr int BS = 2, C_IN = 8, CTX = 1024, TGT = 96;
constexpr int DM = 256, NH = 16, DFF = 1024, NL = 4;
constexpr int NF = 256, TOTAL = 320;
constexpr int NB = 16;
constexpr int DK = 16;
constexpr float EPS = 1e-5f;
constexpr float SCALE = 0.25f;
constexpr int KHEAD = DM * TOTAL;  // 81920

__device__ __forceinline__ ushort f2b(float x) {
    uint u = __float_as_uint(x);
    u += 0x7fff + ((u >> 16) & 1);
    return (ushort)(u >> 16);
}
__device__ __forceinline__ float bu2f(ushort x) { return __uint_as_float(((uint)x) << 16); }
__device__ __forceinline__ float lo2f(uint p) { return __uint_as_float(p << 16); }
__device__ __forceinline__ float hi2f(uint p) { return __uint_as_float(p & 0xffff0000u); }
__device__ __forceinline__ uint pack2(float a, float b) { return (uint)f2b(a) | ((uint)f2b(b) << 16); }

// ---------------- weight convert + transpose: src fp32 (R x C) -> dst bf16 (C x R) ----------------
__global__ void k_convt(const float* __restrict__ src, ushort* __restrict__ dst,
                        int R, int C, int sls, int dls) {
    __shared__ ushort tile[32][33];
    src += (size_t)blockIdx.z * sls;
    dst += (size_t)blockIdx.z * dls;
    int c0 = blockIdx.x * 32, r0 = blockIdx.y * 32;
    int tx = threadIdx.x, ty = threadIdx.y;
    tile[ty][tx] = f2b(src[(r0 + ty) * C + c0 + tx]);
    __syncthreads();
    dst[(c0 + ty) * R + r0 + tx] = tile[tx][ty];
}

// ---------------- RevIN ----------------
__global__ void k_revin(const float* __restrict__ z, const float* __restrict__ rw,
                        const float* __restrict__ rb, float* __restrict__ zn,
                        float* __restrict__ meanv, float* __restrict__ stdv) {
    int bc = blockIdx.x, t = threadIdx.x;
    __shared__ float r1[256], r2[256];
    float s1 = 0.f, s2 = 0.f;
    for (int i = t; i < CTX; i += 256) {
        float x = z[bc * CTX + i];
        s1 += x; s2 += x * x;
    }
    r1[t] = s1; r2[t] = s2; __syncthreads();
    for (int off = 128; off > 0; off >>= 1) {
        if (t < off) { r1[t] += r1[t + off]; r2[t] += r2[t + off]; }
        __syncthreads();
    }
    float m = r1[0] * (1.0f / CTX);
    float var = r2[0] * (1.0f / CTX) - m * m;
    float sd = sqrtf(var + EPS);
    float w = rw[bc % C_IN], b = rb[bc % C_IN];
    float inv = 1.0f / sd;
    for (int i = t; i < CTX; i += 256) {
        float x = z[bc * CTX + i];
        zn[bc * CTX + i] = (x - m) * inv * w + b;
    }
    if (t == 0) { meanv[bc] = m; stdv[bc] = sd; }
}

// ---------------- dual-scale patch embed + positional -> bf16 u ----------------
__global__ void k_embed(const float* __restrict__ zn, const float* __restrict__ Wf,
                        const float* __restrict__ bfv, const float* __restrict__ Wc,
                        const float* __restrict__ bcv, const float* __restrict__ Wpos,
                        ushort* __restrict__ u) {
    int bc = blockIdx.x / TOTAL, p = blockIdx.x % TOTAL, d = threadIdx.x;
    float acc;
    if (p < NF) {
        acc = bfv[d];
        int base = p * 4;
        for (int i = 0; i < 8; i++) {
            int idx = min(base + i, CTX - 1);
            acc += zn[bc * CTX + idx] * Wf[i * DM + d];
        }
    } else {
        int pc = p - NF;
        acc = bcv[d];
        int base = pc * 16;
        for (int i = 0; i < 32; i++) {
            int idx = min(base + i, CTX - 1);
            acc += zn[bc * CTX + idx] * Wc[i * DM + d];
        }
    }
    acc += Wpos[p * DM + d];
    u[(bc * TOTAL + p) * DM + d] = f2b(acc);
}

// ---------------- bf16 MFMA GEMM: C = A(MxK) @ Wt^T + bias; Wt is (N x K) bf16 ----------------
// 64x64 block tile, 4 waves (R6 config — best balance for these small-N GEMMs)
template <int GELU, int QKV>
__global__ __launch_bounds__(256) void k_gemm_mfma(const ushort* __restrict__ A,
                                                   const ushort* __restrict__ Wt,
                                                   const float* __restrict__ b0,
                                                   const float* __restrict__ b1,
                                                   const float* __restrict__ b2,
                                                   ushort* __restrict__ C,
                                                   int M, int N, int K) {
    __shared__ ushort As[64][40];
    __shared__ ushort Bs[64][40];
    int tid = threadIdx.x;
    int wave = tid >> 6, lane = tid & 63;
    int quad = lane >> 4, l16 = lane & 15;
    int m0 = blockIdx.y * 64, n0 = blockIdx.x * 64;

    f32x4 acc[4];
#pragma unroll
    for (int nt = 0; nt < 4; nt++) acc[nt] = (f32x4){0.f, 0.f, 0.f, 0.f};

    int row = tid >> 2, kc = (tid & 3) * 8;
    for (int k0 = 0; k0 < K; k0 += 32) {
        *(short8*)&As[row][kc] = *(const short8*)&A[(m0 + row) * K + k0 + kc];
        *(short8*)&Bs[row][kc] = *(const short8*)&Wt[(n0 + row) * K + k0 + kc];
        __syncthreads();
        short8 af = *(const short8*)&As[wave * 16 + l16][quad * 8];
#pragma unroll
        for (int nt = 0; nt < 4; nt++) {
            short8 bf = *(const short8*)&Bs[nt * 16 + l16][quad * 8];
            acc[nt] = __builtin_amdgcn_mfma_f32_16x16x32_bf16(af, bf, acc[nt], 0, 0, 0);
        }
        __syncthreads();
    }
#pragma unroll
    for (int nt = 0; nt < 4; nt++) {
        int col = n0 + nt * 16 + l16;
        float bi;
        if (QKV) {
            int bs = (n0 + nt * 16) >> 8;
            const float* bp = bs == 0 ? b0 : (bs == 1 ? b1 : b2);
            bi = bp[col & 255];
        } else {
            bi = b0[col];
        }
#pragma unroll
        for (int r = 0; r < 4; r++) {
            int rowm = m0 + wave * 16 + quad * 4 + r;
            float vv = acc[nt][r] + bi;
            if (GELU) vv = vv * 0.5f * (1.0f + erff(vv * 0.70710678118f));
            if (QKV) C[(col >> 8) * (M * DM) + rowm * DM + (col & 255)] = f2b(vv);
            else C[rowm * N + col] = f2b(vv);
        }
    }
}

// ---------------- MFMA fused attention v4: S^T formulation, quad-aliased K (20.5 KB LDS) ----------------
// grid (NB*NH, 5), block 256 (4 waves x 16 q-rows).
// LDS (20480 B): K frags [0,5120) ushorts: slot ((jt*2+half)*16+(j&15))*8+jj  (half = dk-half;
//                quads 2,3 alias half=quad&1 — their products are zeroed by the zero Q-frag);
//                Vt frags [5120,10240): slot 5120+((jt2*4+q)*16+d)*8+jj, permuted j-map
//                j = jt2*32 + (jj<4 ? q*4+jj : 16+q*4+jj-4)  (matches P-frag k-slot order)
// s chunk: sp[((bh*5+iblk)*10+c)*256 + t]; register-native (S^T) layout.
// mode: 0 = store only (layer 0), 1 = load+add+store, 2 = load+add, no store (last layer)
__global__ __launch_bounds__(256, 4) void k_attn(const ushort* __restrict__ qm, const ushort* __restrict__ km,
                                                 const ushort* __restrict__ vm, uint4* __restrict__ sp,
                                                 ushort* __restrict__ ao, int mode) {
    __shared__ ushort sh[10240];
    uint* sh32 = (uint*)sh;
    int bh = blockIdx.x, b = bh >> 4, h = bh & 15;
    int i0 = blockIdx.y * 64;
    int t = threadIdx.x, wave = t >> 6, lane = t & 63, quad = lane >> 4, l16 = lane & 15;
    const short8 zero8 = (short8){0, 0, 0, 0, 0, 0, 0, 0};

    // stage K frags (no zero region: quads 2,3 alias half 0,1 at use site)
    for (int idx = t; idx < 640; idx += 256) {
        int j = idx >> 1, half = idx & 1;
        short8 kv = *(const short8*)&km[(b * TOTAL + j) * DM + h * DK + half * 8];
        int jt = j >> 4, jl = j & 15;
        *(short8*)&sh[((jt * 2 + half) * 16 + jl) * 8] = kv;
    }
    // stage Vt frags (permuted j-map), base ushort 5120
    for (int idx = t; idx < 320; idx += 256) {
        int jp = idx >> 1, dh = idx & 1;
        int j = jp * 2;
        uint4 a = *(const uint4*)&vm[(b * TOTAL + j) * DM + h * DK + dh * 8];
        uint4 bb = *(const uint4*)&vm[(b * TOTAL + j + 1) * DM + h * DK + dh * 8];
        const ushort* ap = (const ushort*)&a;
        const ushort* bp = (const ushort*)&bb;
        int jr = j & 31;
        int q = (jr & 15) >> 2, jj = ((jr >> 4) << 2) + (jr & 3);  // jj even
        int base = 5120 + ((j >> 5) * 4 + q) * 128 + jj;
#pragma unroll
        for (int dd = 0; dd < 8; dd++) {
            int d = dh * 8 + dd;
            uint val = (uint)ap[dd] | ((uint)bp[dd] << 16);
            sh32[(base + d * 8) >> 1] = val;
        }
    }
    // Q frag (B-operand: lane l16 = q-row m, quad = dk-half; quads 2,3 zero)
    short8 qf = zero8;
    if (quad < 2) qf = *(const short8*)&qm[(b * TOTAL + i0 + wave * 16 + l16) * DM + h * DK + quad * 8];
    __syncthreads();

    // S^T = K Q^T: lane (q,m) gets S[m][j], j = nt*16 + q*4 + r, m = l16
    f32x4 acc[20];
#pragma unroll
    for (int nt = 0; nt < 20; nt++) {
        short8 kf = *(const short8*)&sh[((nt * 2 + (quad & 1)) * 16 + l16) * 8];
        acc[nt] = __builtin_amdgcn_mfma_f32_16x16x32_bf16(kf, qf, (f32x4){0.f, 0.f, 0.f, 0.f}, 0, 0, 0);
    }

    // scale + prev add + s writeback (coalesced uint4, bf16-packed)
    int cb = (bh * 5 + (int)blockIdx.y) * 10 * 256 + t;
#pragma unroll
    for (int c = 0; c < 10; c++) {
        float e[8];
#pragma unroll
        for (int j = 0; j < 8; j++) e[j] = acc[2 * c + (j >> 2)][j & 3] * SCALE;
        if (mode) {
            uint4 pv = sp[cb + c * 256];
            e[0] += lo2f(pv.x); e[1] += hi2f(pv.x); e[2] += lo2f(pv.y); e[3] += hi2f(pv.y);
            e[4] += lo2f(pv.z); e[5] += hi2f(pv.z); e[6] += lo2f(pv.w); e[7] += hi2f(pv.w);
        }
        if (mode != 2) {
            uint4 ov;
            ov.x = pack2(e[0], e[1]); ov.y = pack2(e[2], e[3]);
            ov.z = pack2(e[4], e[5]); ov.w = pack2(e[6], e[7]);
            sp[cb + c * 256] = ov;
        }
#pragma unroll
        for (int j = 0; j < 8; j++) acc[2 * c + (j >> 2)][j & 3] = e[j];
    }

    // softmax over j: 80 in-lane + cross-quad (lanes ^16, ^32)
    float mx = -1e30f;
#pragma unroll
    for (int nt = 0; nt < 20; nt++)
#pragma unroll
        for (int r = 0; r < 4; r++) mx = fmaxf(mx, acc[nt][r]);
    mx = fmaxf(mx, __shfl_xor(mx, 16));
    mx = fmaxf(mx, __shfl_xor(mx, 32));
    float sum = 0.f;
#pragma unroll
    for (int nt = 0; nt < 20; nt++)
#pragma unroll
        for (int r = 0; r < 4; r++) { acc[nt][r] = __expf(acc[nt][r] - mx); sum += acc[nt][r]; }
    sum += __shfl_xor(sum, 16);
    sum += __shfl_xor(sum, 32);
    float inv = 1.f / sum;
#pragma unroll
    for (int nt = 0; nt < 20; nt++)
#pragma unroll
        for (int r = 0; r < 4; r++) acc[nt][r] *= inv;

    // PV: o^T = V^T P^T. A = Vt frags (lane l16 = d), B = P^T = own registers (k-permuted).
    f32x4 oacc = (f32x4){0.f, 0.f, 0.f, 0.f};
#pragma unroll
    for (int jt2 = 0; jt2 < 10; jt2++) {
        short8 vt = *(const short8*)&sh[5120 + ((jt2 * 4 + quad) * 16 + l16) * 8];
        union { short8 v; uint u[4]; } pf;
        pf.u[0] = pack2(acc[2 * jt2][0], acc[2 * jt2][1]);
        pf.u[1] = pack2(acc[2 * jt2][2], acc[2 * jt2][3]);
        pf.u[2] = pack2(acc[2 * jt2 + 1][0], acc[2 * jt2 + 1][1]);
        pf.u[3] = pack2(acc[2 * jt2 + 1][2], acc[2 * jt2 + 1][3]);
        oacc = __builtin_amdgcn_mfma_f32_16x16x32_bf16(vt, pf.v, oacc, 0, 0, 0);
    }
    us4 ov4 = (us4){f2b(oacc[0]), f2b(oacc[1]), f2b(oacc[2]), f2b(oacc[3])};
    *(us4*)&ao[(b * TOTAL + i0 + wave * 16 + l16) * DM + h * DK + quad * 4] = ov4;
}

// ---------------- residual add + LayerNorm: wave per row, no LDS/barriers ----------------
__global__ __launch_bounds__(256) void k_add_ln(ushort* __restrict__ u, const ushort* __restrict__ o,
                                                const float* __restrict__ ls, const float* __restrict__ lb) {
    int wave = threadIdx.x >> 6, lane = threadIdx.x & 63;
    int row = blockIdx.x * 4 + wave;
    int d0 = lane * 4;
    uint2 uv = *(const uint2*)&u[row * DM + d0];
    uint2 ov = *(const uint2*)&o[row * DM + d0];
    float x0 = lo2f(uv.x) + lo2f(ov.x);
    float x1 = hi2f(uv.x) + hi2f(ov.x);
    float x2 = lo2f(uv.y) + lo2f(ov.y);
    float x3 = hi2f(uv.y) + hi2f(ov.y);
    float sum = x0 + x1 + x2 + x3;
    float sq = x0 * x0 + x1 * x1 + x2 * x2 + x3 * x3;
#pragma unroll
    for (int off = 1; off < 64; off <<= 1) {
        sum += __shfl_xor(sum, off);
        sq += __shfl_xor(sq, off);
    }
    float m = sum * (1.0f / DM);
    float var = sq * (1.0f / DM) - m * m;
    float rs = rsqrtf(var + EPS);
    f32x4 sc = *(const f32x4*)&ls[d0];
    f32x4 bb = *(const f32x4*)&lb[d0];
    float y0 = (x0 - m) * rs * sc[0] + bb[0];
    float y1 = (x1 - m) * rs * sc[1] + bb[1];
    float y2 = (x2 - m) * rs * sc[2] + bb[2];
    float y3 = (x3 - m) * rs * sc[3] + bb[3];
    uint2 w;
    w.x = pack2(y0, y1); w.y = pack2(y2, y3);
    *(uint2*)&u[row * DM + d0] = w;
}

// ---------------- transpose u (bc,p,d) -> zzT (bc, d*TOTAL+p), bf16 ----------------
__global__ void k_transpose(const ushort* __restrict__ u, ushort* __restrict__ zzT) {
    __shared__ ushort tile[32][34];
    int bc = blockIdx.x, p0 = blockIdx.y * 32, d0 = blockIdx.z * 32;
    int tx = threadIdx.x, ty = threadIdx.y;
    tile[ty][tx] = u[(bc * TOTAL + p0 + ty) * DM + d0 + tx];
    __syncthreads();
    zzT[bc * (DM * TOTAL) + (d0 + ty) * TOTAL + p0 + tx] = tile[tx][ty];
}

// ---------------- head GEMM: MFMA split-K, frags straight from global ----------------
__global__ __launch_bounds__(256) void k_head(const ushort* __restrict__ zzT, const ushort* __restrict__ WhT,
                                              float* __restrict__ acc_head) {
    int t0 = blockIdx.x * 16;
    int wave = threadIdx.x >> 6, lane = threadIdx.x & 63;
    int quad = lane >> 4, l16 = lane & 15;
    int kbeg = (blockIdx.y * 4 + wave) * 1024;
    f32x4 acc = (f32x4){0.f, 0.f, 0.f, 0.f};
    const ushort* za = &zzT[l16 * KHEAD + quad * 8];
    const ushort* wb = &WhT[(t0 + l16) * KHEAD + quad * 8];
#pragma unroll 4
    for (int k = kbeg; k < kbeg + 1024; k += 32) {
        short8 af = *(const short8*)&za[k];
        short8 bf = *(const short8*)&wb[k];
        acc = __builtin_amdgcn_mfma_f32_16x16x32_bf16(af, bf, acc, 0, 0, 0);
    }
#pragma unroll
    for (int r = 0; r < 4; r++)
        atomicAdd(&acc_head[(quad * 4 + r) * TGT + t0 + l16], acc[r]);
}

// ---------------- final ----------------
__global__ void k_final(const float* __restrict__ acc_head, const float* __restrict__ bh,
                        const float* __restrict__ rw, const float* __restrict__ rb,
                        const float* __restrict__ meanv, const float* __restrict__ stdv,
                        float* __restrict__ out) {
    int idx = blockIdx.x * 256 + threadIdx.x;
    if (idx >= NB * TGT) return;
    int bc = idx / TGT, t = idx % TGT, c = bc % C_IN;
    float vv = acc_head[idx] + bh[t];
    vv = (vv - rb[c]) / (rw[c] + EPS * EPS) * stdv[bc] + meanv[bc];
    out[idx] = vv;
}

extern "C" void kernel_launch(void* const* d_in, const int* in_sizes, int n_in,
                              void* d_out, int out_size, void* d_ws, size_t ws_size,
                              hipStream_t stream) {
    const float* z       = (const float*)d_in[0];
    const float* revin_w = (const float*)d_in[1];
    const float* revin_b = (const float*)d_in[2];
    const float* Wf      = (const float*)d_in[3];
    const float* bfv     = (const float*)d_in[4];
    const float* Wc      = (const float*)d_in[5];
    const float* bcv     = (const float*)d_in[6];
    const float* Wpos    = (const float*)d_in[7];
    const float* WQ      = (const float*)d_in[8];
    const float* bQ      = (const float*)d_in[9];
    const float* WK      = (const float*)d_in[10];
    const float* bK      = (const float*)d_in[11];
    const float* WV      = (const float*)d_in[12];
    const float* bV      = (const float*)d_in[13];
    const float* WO      = (const float*)d_in[14];
    const float* bO      = (const float*)d_in[15];
    const float* ln1s    = (const float*)d_in[16];
    const float* ln1b    = (const float*)d_in[17];
    const float* ln2s    = (const float*)d_in[18];
    const float* ln2b    = (const float*)d_in[19];
    const float* F1      = (const float*)d_in[20];
    const float* c1      = (const float*)d_in[21];
    const float* F2      = (const float*)d_in[22];
    const float* c2      = (const float*)d_in[23];
    const float* Wh      = (const float*)d_in[24];
    const float* bh      = (const float*)d_in[25];
    float* out = (float*)d_out;

    const int M = NB * TOTAL;  // 5120

    char* p = (char*)d_ws;
    float* meanv = (float*)p;    p += 16 * 4;
    float* stdv  = (float*)p;    p += 16 * 4;
    float* acc_head = (float*)p; p += NB * TGT * 4;
    p = (char*)(((size_t)p + 255) & ~255ull);
    float* zn = (float*)p;       p += NB * CTX * 4;
    ushort* u    = (ushort*)p;   p += (size_t)M * DM * 2;
    ushort* qkv  = (ushort*)p;   p += (size_t)3 * M * DM * 2;
    ushort* ax   = (ushort*)p;   p += (size_t)M * DM * 2;
    ushort* o    = (ushort*)p;   p += (size_t)M * DM * 2;
    ushort* hbuf = (ushort*)p;   p += (size_t)M * DFF * 2;
    ushort* zzT  = (ushort*)p;   p += (size_t)M * DM * 2;
    ushort* Wtqkv = (ushort*)p;  p += (size_t)NL * 768 * 256 * 2;
    ushort* WtO   = (ushort*)p;  p += (size_t)NL * 256 * 256 * 2;
    ushort* Ft1   = (ushort*)p;  p += (size_t)NL * 1024 * 256 * 2;
    ushort* Ft2   = (ushort*)p;  p += (size_t)NL * 256 * 1024 * 2;
    ushort* WhT   = (ushort*)p;  p += (size_t)TGT * KHEAD * 2;   // 15.7 MB
    p = (char*)(((size_t)p + 255) & ~255ull);
    uint4* sp = (uint4*)p;       p += (size_t)NB * NH * 5 * 10 * 256 * 16;  // 52.4 MB packed bf16 s

    k_convt<<<dim3(8, 8, 4), dim3(32, 32), 0, stream>>>(WQ, Wtqkv + 0,         256, 256, 65536, 768 * 256);
    k_convt<<<dim3(8, 8, 4), dim3(32, 32), 0, stream>>>(WK, Wtqkv + 256 * 256, 256, 256, 65536, 768 * 256);
    k_convt<<<dim3(8, 8, 4), dim3(32, 32), 0, stream>>>(WV, Wtqkv + 512 * 256, 256, 256, 65536, 768 * 256);
    k_convt<<<dim3(8, 8, 4), dim3(32, 32), 0, stream>>>(WO, WtO, 256, 256, 65536, 65536);
    k_convt<<<dim3(32, 8, 4), dim3(32, 32), 0, stream>>>(F1, Ft1, 256, 1024, 262144, 262144);
    k_convt<<<dim3(8, 32, 4), dim3(32, 32), 0, stream>>>(F2, Ft2, 1024, 256, 262144, 262144);
    k_convt<<<dim3(3, 2560, 1), dim3(32, 32), 0, stream>>>(Wh, WhT, KHEAD, TGT, 0, 0);

    k_revin<<<NB, 256, 0, stream>>>(z, revin_w, revin_b, zn, meanv, stdv);
    k_embed<<<NB * TOTAL, 256, 0, stream>>>(zn, Wf, bfv, Wc, bcv, Wpos, u);

    for (int l = 0; l < NL; l++) {
        int mode = (l == 0) ? 0 : (l == NL - 1 ? 2 : 1);
        k_gemm_mfma<0, 1><<<dim3(12, 80), 256, 0, stream>>>(
            u, Wtqkv + (size_t)l * 768 * 256, bQ + l * DM, bK + l * DM, bV + l * DM, qkv, M, 768, 256);
        k_attn<<<dim3(NB * NH, 5), 256, 0, stream>>>(qkv, qkv + M * DM, qkv + 2 * M * DM, sp, ax, mode);
        k_gemm_mfma<0, 0><<<dim3(4, 80), 256, 0, stream>>>(
            ax, WtO + (size_t)l * 65536, bO + l * DM, bO + l * DM, bO + l * DM, o, M, 256, 256);
        k_add_ln<<<M / 4, 256, 0, stream>>>(u, o, ln1s + l * DM, ln1b + l * DM);
        k_gemm_mfma<1, 0><<<dim3(16, 80), 256, 0, stream>>>(
            u, Ft1 + (size_t)l * 262144, c1 + l * DFF, c1, c1, hbuf, M, 1024, 256);
        k_gemm_mfma<0, 0><<<dim3(4, 80), 256, 0, stream>>>(
            hbuf, Ft2 + (size_t)l * 262144, c2 + l * DM, c2, c2, o, M, 256, 1024);
        k_add_ln<<<M / 4, 256, 0, stream>>>(u, o, ln2s + l * DM, ln2b + l * DM);
    }

    k_transpose<<<dim3(NB, TOTAL / 32, DM / 32), dim3(32, 32), 0, stream>>>(u, zzT);
    hipMemsetAsync(acc_head, 0, NB * TGT * sizeof(float), stream);
    k_head<<<dim3(TGT / 16, 20), 256, 0, stream>>>(zzT, WhT, acc_head);
    k_final<<<(NB * TGT + 255) / 256, 256, 0, stream>>>(acc_head, bh, revin_w, revin_b, meanv, stdv, out);
}